// Round 17
// baseline (184.218 us; speedup 1.0000x reference)
//
#include <hip/hip_runtime.h>
#include <math.h>

// PNANet on MI355X, round 17: registerized b2 aggregation.
//  * agg producer-thread layout == MFMA A-frag consumer layout -> stats built
//    directly in registers (8 f16x8 frags/thread); aggS LDS (33.8KB) deleted,
//    one barrier and all aggS traffic/conflicts gone; b2 LDS 41KB -> 7KB.
//  * everything else identical to round 16.

#define NGRAPH 128
#define NPG    512
#define NN     (NGRAPH*NPG)   // 65536
#define KNB    7

constexpr double AVG_DEG_LOG_D = 2.0239670479173344;  // (100*ln6+200*ln7+700*ln8)/1000
constexpr double LOG8_D        = 2.0794415416798357;

typedef _Float16 f16x8 __attribute__((ext_vector_type(8)));
typedef _Float16 h2    __attribute__((ext_vector_type(2)));
typedef float    f32x4 __attribute__((ext_vector_type(4)));

__device__ __forceinline__ unsigned short f2h(float x) {
    _Float16 h = (_Float16)x;
    return __builtin_bit_cast(unsigned short, h);
}

// ---------------------------------------------------------------- weight prep
__global__ __launch_bounds__(256) void prep_kernel(
    const float* __restrict__ Wpost1, const float* __restrict__ Wpost2,
    const float* __restrict__ Wpre2,  const float* __restrict__ Wlin2,
    const float* __restrict__ Wlin1,
    unsigned short* __restrict__ Wf1p, unsigned short* __restrict__ Wf1l,
    unsigned short* __restrict__ Wfv, unsigned short* __restrict__ Wfu,
    unsigned short* __restrict__ Wfp, unsigned short* __restrict__ Wfl)
{
    const float AMP = (float)(LOG8_D / AVG_DEG_LOG_D);
    const float ATT = (float)(AVG_DEG_LOG_D / LOG8_D);
    for (int i = blockIdx.x*256 + threadIdx.x; i < 90112; i += gridDim.x*256) {
        if (i < 4096) {
            // Wf1p: [t][kk<2][lane<64][j<8]; k = kk*32+(lane>>4)*8+j; col = lane&15
            int t = i >> 10, kk = (i >> 9) & 1, lane = (i >> 3) & 63, j = i & 7;
            int k = kk*32 + ((lane >> 4) << 3) + j;
            int col = lane & 15;
            float val;
            if (k < 8)       val = Wpost1[(t*104 + k)*16 + col];
            else if (k < 40) {
                int g2 = k - 8;
                val = Wpost1[(t*104 +  8 + g2)*16 + col]
                    + AMP*Wpost1[(t*104 + 40 + g2)*16 + col]
                    + ATT*Wpost1[(t*104 + 72 + g2)*16 + col];
            } else val = 0.f;
            Wf1p[i] = f2h(val);
        } else if (i < 8192) {
            // Wf1l: [kk<2][tile<4][lane<64][j<8]
            int jj = i - 4096;
            int kk = jj >> 11, tile = (jj >> 9) & 3, lane = (jj >> 3) & 63, j = jj & 7;
            int k = kk*32 + ((lane >> 4) << 3) + j;
            int col = tile*16 + (lane & 15);
            Wf1l[jj] = f2h(Wlin1[k*64 + col]);
        } else if (i < 24576) {
            // Wfv: [kk<2][ct<16][lane<64][j<8] f16; v cols 0..255
            int jj = i - 8192;
            int kk = jj >> 13, ct = (jj >> 9) & 15, lane = (jj >> 3) & 63, jf = jj & 7;
            int k   = kk*32 + ((lane >> 4) << 3) + jf;
            int col = ct*16 + (lane & 15);
            int t = col >> 6, f = col & 63;
            Wfv[jj] = f2h(Wpre2[(t*128 + 64 + k)*64 + f]);
        } else if (i < 32768) {
            // Wfu_fold: [t][kk<2][c<2][lane<64][j<8]
            int jj = i - 24576;
            int t = jj >> 11, kk = (jj >> 10) & 1, c = (jj >> 9) & 1, lane = (jj >> 3) & 63, jf = jj & 7;
            int k   = kk*32 + ((lane >> 4) << 3) + jf;
            int col = c*16 + (lane & 15);
            float acc = 0.f;
            for (int f = 0; f < 64; ++f) {
                float wu = 0.f;
#pragma unroll
                for (int s = 0; s < 3; ++s) {
                    int g2 = s*64 + f;   // mean, min, max rows
                    wu += Wpost2[(t*832 +  64 + g2)*32 + col]
                        + AMP*Wpost2[(t*832 + 320 + g2)*32 + col]
                        + ATT*Wpost2[(t*832 + 576 + g2)*32 + col];
                }
                acc += Wpre2[(t*128 + k)*64 + f] * wu;
            }
            Wfu[jj] = f2h(acc);
        } else if (i < 73728) {
            // Wfrag_post: [t][kk<10][c<2][lane<64][j<8], f16
            int jj = i - 32768;
            int t = jj / 10240, r = jj % 10240;
            int kk = r / 1024, r2 = r % 1024;
            int c = r2 >> 9, lane = (r2 >> 3) & 63, jf = r2 & 7;
            int G   = kk*32 + ((lane >> 4) << 3) + jf;
            int col = c*16 + (lane & 15);
            float val;
            if (G < 64) val = Wpost2[(t*832 + G)*32 + col];
            else {
                int g2 = G - 64;
                val = Wpost2[(t*832 +  64 + g2)*32 + col]
                    + AMP*Wpost2[(t*832 + 320 + g2)*32 + col]
                    + ATT*Wpost2[(t*832 + 576 + g2)*32 + col];
            }
            Wfp[jj] = f2h(val);
        } else {
            // Wfrag_lin: [kk<4][tile<8][lane<64][j<8], f16
            int jj = i - 73728;
            int kk = jj / 4096, r = jj % 4096;
            int tile = r >> 9, lane = (r >> 3) & 63, jf = r & 7;
            int k   = kk*32 + ((lane >> 4) << 3) + jf;
            int col = tile*16 + (lane & 15);
            Wfl[jj] = f2h(Wlin2[k*128 + col]);
        }
    }
}

// ---------------------------------------------------------------- kNN part: (node-half, cand-quarter); 128 cands/thread
__global__ __launch_bounds__(256) void knn_part_kernel(const float* __restrict__ pos, float2* __restrict__ part)
{
    __shared__ float4 cposS[128];
    const int b = blockIdx.x;
    const int g = b >> 3, h = (b >> 2) & 1, q = b & 3;
    const int gb = g * NPG;
    const int cbase = q * 128;
    if (threadIdx.x < 128) {
        int j = cbase + threadIdx.x;
        cposS[threadIdx.x] = make_float4(pos[(gb+j)*3+0], pos[(gb+j)*3+1], pos[(gb+j)*3+2], 0.f);
    }
    __syncthreads();
    const int i = h*256 + threadIdx.x;
    const float px = pos[(gb+i)*3+0], py = pos[(gb+i)*3+1], pz = pos[(gb+i)*3+2];
    float bd[KNB]; int bi[KNB];
#pragma unroll
    for (int e = 0; e < KNB; ++e) { bd[e] = 3.0e38f; bi[e] = -1; }
#pragma unroll 4
    for (int j = 0; j < 128; ++j) {
        float4 pj = cposS[j];
        float dx = px - pj.x, dy = py - pj.y, dz = pz - pj.z;
        float d2 = __fadd_rn(__fadd_rn(__fmul_rn(dx,dx), __fmul_rn(dy,dy)), __fmul_rn(dz,dz));
        if (cbase + j == i) d2 = __builtin_inff();
        bool cmp[KNB];
#pragma unroll
        for (int e = 0; e < KNB; ++e) cmp[e] = d2 < bd[e];
#pragma unroll
        for (int e = KNB-1; e >= 1; --e) {
            bd[e] = cmp[e-1] ? bd[e-1] : (cmp[e] ? d2 : bd[e]);
            bi[e] = cmp[e-1] ? bi[e-1] : (cmp[e] ? cbase + j : bi[e]);
        }
        bd[0] = cmp[0] ? d2 : bd[0];
        bi[0] = cmp[0] ? cbase + j : bi[0];
    }
    float2* dst = &part[((size_t)(g*NPG + i)*4 + q)*KNB];
#pragma unroll
    for (int e = 0; e < KNB; ++e) dst[e] = make_float2(bd[e], __int_as_float(bi[e]));
}

// ---------------------------------------------------------------- kNN merge: 1 thread/node, 28 pairs -> top-7
__global__ __launch_bounds__(256) void knn_merge_kernel(const float2* __restrict__ part, int* __restrict__ nbr)
{
    const int n = blockIdx.x*256 + threadIdx.x;
    const float4* p4 = (const float4*)&part[(size_t)n*28];
    float bd[KNB]; int bi[KNB];
#pragma unroll
    for (int e = 0; e < KNB; ++e) { bd[e] = 3.0e38f; bi[e] = -1; }
#pragma unroll
    for (int m4 = 0; m4 < 14; ++m4) {
        float4 pr = p4[m4];
#pragma unroll
        for (int half = 0; half < 2; ++half) {
            float d2  = half ? pr.z : pr.x;
            int   idx = __float_as_int(half ? pr.w : pr.y);
            bool cmp[KNB];
#pragma unroll
            for (int e = 0; e < KNB; ++e) cmp[e] = d2 < bd[e];
#pragma unroll
            for (int e = KNB-1; e >= 1; --e) {
                bd[e] = cmp[e-1] ? bd[e-1] : (cmp[e] ? d2 : bd[e]);
                bi[e] = cmp[e-1] ? bi[e-1] : (cmp[e] ? idx : bi[e]);
            }
            bd[0] = cmp[0] ? d2 : bd[0];
            bi[0] = cmp[0] ? idx : bi[0];
        }
    }
    const int gb = n & ~(NPG-1);
#pragma unroll
    for (int e = 0; e < KNB; ++e) nbr[n*KNB + e] = gb + bi[e];
}

// ---------------------------------------------------------------- layer1: u1,v1 [N,32]
__global__ __launch_bounds__(256) void a1_kernel(
    const float* __restrict__ x, const float* __restrict__ Wpre1, const float* __restrict__ bpre1,
    float* __restrict__ u1, float* __restrict__ v1)
{
    __shared__ float wS[512];
    __shared__ float bS[32];
    const int tid = threadIdx.x;
    wS[tid] = Wpre1[tid]; wS[tid+256] = Wpre1[tid+256];
    if (tid < 32) bS[tid] = bpre1[tid];
    __syncthreads();
    const int n  = blockIdx.x*8 + (tid>>5);
    const int tf = tid & 31;
    const int t = tf >> 3, f = tf & 7;
    float u = bS[tf], v = 0.f;
#pragma unroll
    for (int e = 0; e < 8; ++e) {
        float xv = x[n*8+e];
        u += xv * wS[(t*16 + e)*8 + f];
        v += xv * wS[(t*16 + 8 + e)*8 + f];
    }
    u1[n*32+tf] = u;
    v1[n*32+tf] = v;
}

// ---------------------------------------------------------------- layer1 fused (MFMA f16): agg + post + lin -> y1 [N,64]
__global__ __launch_bounds__(256) void b1_kernel(
    const float* __restrict__ x, const int* __restrict__ nbr,
    const float* __restrict__ u1, const float* __restrict__ v1,
    const unsigned short* __restrict__ Wf1p, const unsigned short* __restrict__ Wf1l,
    float* __restrict__ y1)
{
    __shared__ int nbrsS[112];
    __shared__ __align__(16) unsigned short actS[64*72];
    __shared__ __align__(16) unsigned short postS[16*72];
    const int tid  = threadIdx.x;
    const int base = blockIdx.x * 16;
    if (tid < 112) nbrsS[tid] = nbr[base*7 + tid];
    for (int i = tid; i < 384; i += 256) {
        int r = i / 6, gq = i - 6*r;
        *(ushort4*)&actS[r*72 + 40 + gq*4] = make_ushort4(0,0,0,0);
    }
#pragma unroll
    for (int it = 0; it < 2; ++it) {
        int i = tid + it*256;
        int n = i >> 5, r2 = i & 31, t = r2 >> 3, f = r2 & 7;
        actS[(n*4 + t)*72 + f] = f2h(x[(base+n)*8 + f]);
    }
    __syncthreads();
    {
        const int n = tid >> 4, cp = tid & 15;
        const int tf0 = cp*2, t = tf0 >> 3, f0 = tf0 & 7;
        float2 uu = *(const float2*)&u1[(base+n)*32 + tf0];
        float s0=0.f,s1=0.f,q0=0.f,q1=0.f;
        float mn0=3e38f,mn1=3e38f,mx0=-3e38f,mx1=-3e38f;
#pragma unroll
        for (int e = 0; e < 7; ++e) {
            float2 vv = *(const float2*)&v1[nbrsS[n*7+e]*32 + tf0];
            s0 += vv.x; q0 += vv.x*vv.x; mn0 = fminf(mn0, vv.x); mx0 = fmaxf(mx0, vv.x);
            s1 += vv.y; q1 += vv.y*vv.y; mn1 = fminf(mn1, vv.y); mx1 = fmaxf(mx1, vv.y);
        }
        float me0 = s0*(1.f/7.f), me1 = s1*(1.f/7.f);
        float sd0 = sqrtf(fmaxf(q0*(1.f/7.f) - me0*me0, 0.f) + 1e-5f);
        float sd1 = sqrtf(fmaxf(q1*(1.f/7.f) - me1*me1, 0.f) + 1e-5f);
        const int row = (n*4 + t)*72;
        ushort2 w_;
        w_.x = f2h(uu.x + me0); w_.y = f2h(uu.y + me1); *(ushort2*)&actS[row +  8 + f0] = w_;
        w_.x = f2h(uu.x + mn0); w_.y = f2h(uu.y + mn1); *(ushort2*)&actS[row + 16 + f0] = w_;
        w_.x = f2h(uu.x + mx0); w_.y = f2h(uu.y + mx1); *(ushort2*)&actS[row + 24 + f0] = w_;
        w_.x = f2h(sd0);        w_.y = f2h(sd1);        *(ushort2*)&actS[row + 32 + f0] = w_;
    }
    __syncthreads();
    const int l = tid & 63, w = tid >> 6;
    const int lr = l & 15, lk = l >> 4;
    f32x4 acc = {0.f,0.f,0.f,0.f};
    {
        const f16x8* WB = (const f16x8*)Wf1p;
#pragma unroll
        for (int kk = 0; kk < 2; ++kk) {
            f16x8 a = *(const f16x8*)&actS[(lr*4 + w)*72 + kk*32 + lk*8];
            f16x8 b = WB[(w*2 + kk)*64 + l];
            acc = __builtin_amdgcn_mfma_f32_16x16x32_f16(a, b, acc, 0, 0, 0);
        }
    }
#pragma unroll
    for (int j = 0; j < 4; ++j)
        postS[(lk*4 + j)*72 + w*16 + lr] = f2h(acc[j]);
    __syncthreads();
    f32x4 d = {0.f,0.f,0.f,0.f};
    {
        const f16x8* WB = (const f16x8*)Wf1l;
#pragma unroll
        for (int kk = 0; kk < 2; ++kk) {
            f16x8 a = *(const f16x8*)&postS[lr*72 + kk*32 + lk*8];
            f16x8 b = WB[(kk*4 + w)*64 + l];
            d = __builtin_amdgcn_mfma_f32_16x16x32_f16(a, b, d, 0, 0, 0);
        }
    }
    // mixing-linear bias cancels in BN1 (per-column constant) — omitted.
#pragma unroll
    for (int j = 0; j < 4; ++j)
        y1[(base + lk*4 + j)*64 + w*16 + lr] = d[j];
}

// ---------------------------------------------------------------- BN stats: 1024 blocks, float4, LDS tree -> partials
template<int C>
__global__ __launch_bounds__(256) void bn_stats_kernel(
    const float* __restrict__ y, float* __restrict__ Ps, float* __restrict__ Pq)
{
    constexpr int IT     = (NN/1024)*(C/4)/256;
    constexpr int GROUPS = C/4;
    constexpr int REPS   = 256/GROUPS;
    const int tid = threadIdx.x;
    const float4* y4 = (const float4*)y + (size_t)blockIdx.x*256*IT;
    float4 s = make_float4(0.f,0.f,0.f,0.f), q = make_float4(0.f,0.f,0.f,0.f);
#pragma unroll
    for (int it = 0; it < IT; ++it) {
        float4 v = y4[it*256 + tid];
        s.x += v.x; s.y += v.y; s.z += v.z; s.w += v.w;
        q.x += v.x*v.x; q.y += v.y*v.y; q.z += v.z*v.z; q.w += v.w*v.w;
    }
    __shared__ float4 sS[256], qS[256];
    sS[tid] = s; qS[tid] = q;
    __syncthreads();
#pragma unroll
    for (int step = REPS/2; step >= 1; step >>= 1) {
        if (tid < step*GROUPS) {
            float4 s2 = sS[tid + step*GROUPS], q2 = qS[tid + step*GROUPS];
            float4 ss = sS[tid], qq = qS[tid];
            ss.x += s2.x; ss.y += s2.y; ss.z += s2.z; ss.w += s2.w;
            qq.x += q2.x; qq.y += q2.y; qq.z += q2.z; qq.w += q2.w;
            sS[tid] = ss; qS[tid] = qq;
        }
        __syncthreads();
    }
    if (tid < GROUPS) {
        ((float4*)&Ps[(size_t)blockIdx.x*C])[tid] = sS[tid];
        ((float4*)&Pq[(size_t)blockIdx.x*C])[tid] = qS[tid];
    }
}

// ---------------------------------------------------------------- finA: 64 blocks, sum 16 partial-rows
template<int C>
__global__ __launch_bounds__(C) void finA_kernel(
    const float* __restrict__ Ps, const float* __restrict__ Pq,
    float* __restrict__ As, float* __restrict__ Aq)
{
    const int c = threadIdx.x, b = blockIdx.x;
    float s = 0.f, q = 0.f;
#pragma unroll
    for (int i = 0; i < 16; ++i) {
        s += Ps[(b*16 + i)*C + c];
        q += Pq[(b*16 + i)*C + c];
    }
    As[b*C + c] = s;
    Aq[b*C + c] = q;
}

// ---------------------------------------------------------------- finalize BN -> scale/shift (sums 64)
template<int C>
__global__ __launch_bounds__(C) void fin_kernel(
    const float* __restrict__ As, const float* __restrict__ Aq,
    const float* __restrict__ g, const float* __restrict__ b,
    float* __restrict__ scO, float* __restrict__ shO)
{
    const int c = threadIdx.x;
    float s = 0.f, q = 0.f;
#pragma unroll 8
    for (int i = 0; i < 64; ++i) { s += As[i*C + c]; q += Aq[i*C + c]; }
    const float inv = 1.f/(float)NN;
    float mu  = s*inv;
    float var = q*inv - mu*mu;
    float sc  = g[c]*rsqrtf(var + 1e-5f);
    scO[c] = sc;
    shO[c] = b[c] - mu*sc;
}

// ---------------------------------------------------------------- layer2 pre (MFMA f16): v2 [N][256] f16 (v only)
__global__ __launch_bounds__(256) void a2_kernel(
    const float* __restrict__ y1raw, const float* __restrict__ sc1, const float* __restrict__ sh1,
    const unsigned short* __restrict__ Wfv,
    unsigned short* __restrict__ v2)
{
    __shared__ __align__(16) unsigned short a1S[64*72];
    const int tid  = threadIdx.x;
    const int base = blockIdx.x * 64;
#pragma unroll
    for (int it = 0; it < 4; ++it) {
        int i = tid + it*256;
        float4 vv = ((const float4*)y1raw)[blockIdx.x*1024 + i];
        int n = i >> 4, c0 = (i & 15)*4;
        float c_[4] = {vv.x, vv.y, vv.z, vv.w};
#pragma unroll
        for (int j = 0; j < 4; ++j) {
            int c = c0 + j;
            a1S[n*72 + c] = f2h(fmaxf(c_[j]*sc1[c] + sh1[c], 0.f));
        }
    }
    __syncthreads();
    const int l = tid & 63, w = tid >> 6;
    const int lr = l & 15, lk = l >> 4;
    const f16x8 a0  = *(const f16x8*)&a1S[(w*16 + lr)*72 +      lk*8];
    const f16x8 a1f = *(const f16x8*)&a1S[(w*16 + lr)*72 + 32 + lk*8];
    const f16x8* WB = (const f16x8*)Wfv;
#pragma unroll 4
    for (int ct = 0; ct < 16; ++ct) {
        f32x4 acc = {0.f,0.f,0.f,0.f};
        f16x8 b0 = WB[ct*64 + l];
        f16x8 b1 = WB[(16 + ct)*64 + l];
        acc = __builtin_amdgcn_mfma_f32_16x16x32_f16(a0,  b0, acc, 0, 0, 0);
        acc = __builtin_amdgcn_mfma_f32_16x16x32_f16(a1f, b1, acc, 0, 0, 0);
        const int col = ct*16 + lr;
#pragma unroll
        for (int j = 0; j < 4; ++j)
            v2[(size_t)(base + w*16 + lk*4 + j)*256 + col] = f2h(acc[j]);
    }
}

// ---------------------------------------------------------------- layer2 fused (MFMA f16): register-agg + post + lin -> y2
// Thread (lr,lk,w): gathers v2 cols {w*64+lk*8, w*64+32+lk*8} of node lr's 7
// neighbors; stats -> 8 A-frags in registers == MFMA A layout. No aggS.
__global__ __launch_bounds__(256) void b2_kernel(
    const int* __restrict__ nbr, const float* __restrict__ y1raw,
    const float* __restrict__ sc1, const float* __restrict__ sh1,
    const unsigned short* __restrict__ v2,
    const unsigned short* __restrict__ Wfu,
    const unsigned short* __restrict__ Wfp, const unsigned short* __restrict__ Wfl,
    float* __restrict__ y2)
{
    __shared__ int nbrsS[112];
    __shared__ __align__(16) unsigned short a1S[16*72];
    __shared__ __align__(16) unsigned short postS[16*136];

    const int tid = threadIdx.x;
    const int ob   = blockIdx.x;
    const int xcd  = ob & 7, slot = ob >> 3;
    const int gph  = ((slot >> 5) << 3) + xcd;
    const int sub  = slot & 31;
    const int base = gph*NPG + sub*16;

    if (tid < 112) nbrsS[tid] = nbr[base*7 + tid];
    for (int i = tid; i < 1024; i += 256) {
        int c = i & 63, n = i >> 6;
        float a = fmaxf(y1raw[base*64 + i]*sc1[c] + sh1[c], 0.f);
        a1S[n*72 + c] = f2h(a);
    }
    __syncthreads();
    const int l = tid & 63, w = tid >> 6;
    const int lr = l & 15, lk = l >> 4;
    // ---- register aggregation: node lr, tower w, col groups g0/g1 (8 f16 each)
    const int g0 = w*64 + lk*8;
    const int g1 = g0 + 32;
    const h2 inv7 = { (_Float16)(1.f/7.f), (_Float16)(1.f/7.f) };
    h2 z = { (_Float16)0.f, (_Float16)0.f };
    h2 sA[4] = {z,z,z,z}, qA[4] = {z,z,z,z};
    h2 sB[4] = {z,z,z,z}, qB[4] = {z,z,z,z};
    h2 mnA[4], mxA[4], mnB[4], mxB[4];
#pragma unroll
    for (int p = 0; p < 4; ++p) {
        mnA[p] = h2{ (_Float16)65504.f, (_Float16)65504.f };  mnB[p] = mnA[p];
        mxA[p] = h2{ (_Float16)-65504.f, (_Float16)-65504.f }; mxB[p] = mxA[p];
    }
#pragma unroll
    for (int e = 0; e < 7; ++e) {
        const size_t nb = (size_t)nbrsS[lr*7 + e] * 256;
        uint4 va = *(const uint4*)&v2[nb + g0];
        uint4 vb = *(const uint4*)&v2[nb + g1];
        unsigned aw[4] = {va.x, va.y, va.z, va.w};
        unsigned bw[4] = {vb.x, vb.y, vb.z, vb.w};
#pragma unroll
        for (int p = 0; p < 4; ++p) {
            h2 v = __builtin_bit_cast(h2, aw[p]);
            sA[p] += v; qA[p] += v*v;
            mnA[p] = __builtin_elementwise_min(mnA[p], v);
            mxA[p] = __builtin_elementwise_max(mxA[p], v);
            h2 u = __builtin_bit_cast(h2, bw[p]);
            sB[p] += u; qB[p] += u*u;
            mnB[p] = __builtin_elementwise_min(mnB[p], u);
            mxB[p] = __builtin_elementwise_max(mxB[p], u);
        }
    }
    // finalize stats -> 8 register A-frags (mean/min/max/std x groups 0,1)
    unsigned meAW[4], sdAW[4], meBW[4], sdBW[4];
#pragma unroll
    for (int p = 0; p < 4; ++p) {
        h2 meA = sA[p]*inv7;
        h2 meB = sB[p]*inv7;
        float a0 = (float)meA[0], a1v = (float)meA[1];
        float b0 = (float)meB[0], b1v = (float)meB[1];
        float sa0 = sqrtf(fmaxf(fmaf((float)qA[p][0], 1.f/7.f, -a0*a0), 0.f) + 1e-5f);
        float sa1 = sqrtf(fmaxf(fmaf((float)qA[p][1], 1.f/7.f, -a1v*a1v), 0.f) + 1e-5f);
        float sb0 = sqrtf(fmaxf(fmaf((float)qB[p][0], 1.f/7.f, -b0*b0), 0.f) + 1e-5f);
        float sb1 = sqrtf(fmaxf(fmaf((float)qB[p][1], 1.f/7.f, -b1v*b1v), 0.f) + 1e-5f);
        h2 sdA = { (_Float16)sa0, (_Float16)sa1 };
        h2 sdB = { (_Float16)sb0, (_Float16)sb1 };
        meAW[p] = __builtin_bit_cast(unsigned, meA);
        meBW[p] = __builtin_bit_cast(unsigned, meB);
        sdAW[p] = __builtin_bit_cast(unsigned, sdA);
        sdBW[p] = __builtin_bit_cast(unsigned, sdB);
    }
    f16x8 fr[8];
    fr[0] = __builtin_bit_cast(f16x8, make_uint4(meAW[0], meAW[1], meAW[2], meAW[3]));
    fr[1] = __builtin_bit_cast(f16x8, make_uint4(meBW[0], meBW[1], meBW[2], meBW[3]));
    fr[2] = __builtin_bit_cast(f16x8, make_uint4(__builtin_bit_cast(unsigned, mnA[0]), __builtin_bit_cast(unsigned, mnA[1]),
                                                 __builtin_bit_cast(unsigned, mnA[2]), __builtin_bit_cast(unsigned, mnA[3])));
    fr[3] = __builtin_bit_cast(f16x8, make_uint4(__builtin_bit_cast(unsigned, mnB[0]), __builtin_bit_cast(unsigned, mnB[1]),
                                                 __builtin_bit_cast(unsigned, mnB[2]), __builtin_bit_cast(unsigned, mnB[3])));
    fr[4] = __builtin_bit_cast(f16x8, make_uint4(__builtin_bit_cast(unsigned, mxA[0]), __builtin_bit_cast(unsigned, mxA[1]),
                                                 __builtin_bit_cast(unsigned, mxA[2]), __builtin_bit_cast(unsigned, mxA[3])));
    fr[5] = __builtin_bit_cast(f16x8, make_uint4(__builtin_bit_cast(unsigned, mxB[0]), __builtin_bit_cast(unsigned, mxB[1]),
                                                 __builtin_bit_cast(unsigned, mxB[2]), __builtin_bit_cast(unsigned, mxB[3])));
    fr[6] = __builtin_bit_cast(f16x8, make_uint4(sdAW[0], sdAW[1], sdAW[2], sdAW[3]));
    fr[7] = __builtin_bit_cast(f16x8, make_uint4(sdBW[0], sdBW[1], sdBW[2], sdBW[3]));
    // ---- post GEMM (tower w): 2 a1-direct + 2 a1-ufold + 8 register-agg chunks
    f32x4 acc0 = {0.f,0.f,0.f,0.f}, acc1 = {0.f,0.f,0.f,0.f};
    {
        const f16x8* WP = (const f16x8*)Wfp;
        const f16x8* WU = (const f16x8*)Wfu;
#pragma unroll
        for (int kk = 0; kk < 2; ++kk) {
            f16x8 a = *(const f16x8*)&a1S[lr*72 + kk*32 + lk*8];
            f16x8 b0 = WP[((w*10 + kk)*2 + 0)*64 + l];
            f16x8 b1 = WP[((w*10 + kk)*2 + 1)*64 + l];
            acc0 = __builtin_amdgcn_mfma_f32_16x16x32_f16(a, b0, acc0, 0, 0, 0);
            acc1 = __builtin_amdgcn_mfma_f32_16x16x32_f16(a, b1, acc1, 0, 0, 0);
        }
#pragma unroll
        for (int kk = 0; kk < 2; ++kk) {
            f16x8 a = *(const f16x8*)&a1S[lr*72 + kk*32 + lk*8];
            f16x8 b0 = WU[((w*2 + kk)*2 + 0)*64 + l];
            f16x8 b1 = WU[((w*2 + kk)*2 + 1)*64 + l];
            acc0 = __builtin_amdgcn_mfma_f32_16x16x32_f16(a, b0, acc0, 0, 0, 0);
            acc1 = __builtin_amdgcn_mfma_f32_16x16x32_f16(a, b1, acc1, 0, 0, 0);
        }
#pragma unroll
        for (int c = 0; c < 8; ++c) {
            f16x8 b0 = WP[((w*10 + c + 2)*2 + 0)*64 + l];
            f16x8 b1 = WP[((w*10 + c + 2)*2 + 1)*64 + l];
            acc0 = __builtin_amdgcn_mfma_f32_16x16x32_f16(fr[c], b0, acc0, 0, 0, 0);
            acc1 = __builtin_amdgcn_mfma_f32_16x16x32_f16(fr[c], b1, acc1, 0, 0, 0);
        }
    }
#pragma unroll
    for (int j = 0; j < 4; ++j) {
        const int row = lk*4 + j;
        postS[row*136 + w*32 +      lr] = f2h(acc0[j]);
        postS[row*136 + w*32 + 16 + lr] = f2h(acc1[j]);
    }
    __syncthreads();
    // ---- lin GEMM (cols 32w..32w+31): K=128; bias cancels in BN2 — omitted
    f32x4 d0 = {0.f,0.f,0.f,0.f}, d1 = {0.f,0.f,0.f,0.f};
    {
        const f16x8* WB = (const f16x8*)Wfl;
#pragma unroll
        for (int kk = 0; kk < 4; ++kk) {
            f16x8 a = *(const f16x8*)&postS[lr*136 + kk*32 + lk*8];
            f16x8 b0 = WB[(kk*8 + 2*w + 0)*64 + l];
            f16x8 b1 = WB[(kk*8 + 2*w + 1)*64 + l];
            d0 = __builtin_amdgcn_mfma_f32_16x16x32_f16(a, b0, d0, 0, 0, 0);
            d1 = __builtin_amdgcn_mfma_f32_16x16x32_f16(a, b1, d1, 0, 0, 0);
        }
    }
#pragma unroll
    for (int j = 0; j < 4; ++j) {
        const int row = lk*4 + j;
        y2[(base + row)*128 + w*32 +      lr] = d0[j];
        y2[(base + row)*128 + w*32 + 16 + lr] = d1[j];
    }
}

// ---------------------------------------------------------------- pool part: BN2+relu+64-row partial sums (1024 blocks)
__global__ __launch_bounds__(128) void pool_part_kernel(
    const float* __restrict__ y2, const float* __restrict__ sc2, const float* __restrict__ sh2,
    float* __restrict__ Pp)
{
    const int c = threadIdx.x;
    const int b = blockIdx.x;
    const float sc = sc2[c];
    const float sh = sh2[c];
    float acc = 0.f;
    const size_t base = (size_t)b*64*128 + c;
#pragma unroll 4
    for (int i = 0; i < 64; ++i)
        acc += fmaxf(y2[base + (size_t)i*128]*sc + sh, 0.f);
    Pp[b*128 + c] = acc;
}

// ---------------------------------------------------------------- pool finalize: sum 8 chunks -> out [128,128]
__global__ __launch_bounds__(128) void pool_fin_kernel(
    const float* __restrict__ Pp, float* __restrict__ out)
{
    const int c = threadIdx.x, g = blockIdx.x;
    float acc = 0.f;
#pragma unroll
    for (int i = 0; i < 8; ++i) acc += Pp[(g*8 + i)*128 + c];
    out[g*128 + c] = acc * (1.f/(float)NPG);
}

// ---------------------------------------------------------------- launcher
extern "C" void kernel_launch(void* const* d_in, const int* in_sizes, int n_in,
                              void* d_out, int out_size, void* d_ws, size_t ws_size,
                              hipStream_t stream)
{
    const float* x      = (const float*)d_in[0];
    const float* pos    = (const float*)d_in[1];
    const float* Wpre1  = (const float*)d_in[2];
    const float* bpre1  = (const float*)d_in[3];
    const float* Wpost1 = (const float*)d_in[4];
    const float* bpost1 = (const float*)d_in[5];
    const float* Wlin1  = (const float*)d_in[6];
    const float* blin1  = (const float*)d_in[7];
    const float* bn1g   = (const float*)d_in[8];
    const float* bn1b   = (const float*)d_in[9];
    const float* Wpre2  = (const float*)d_in[10];
    const float* bpre2  = (const float*)d_in[11];
    const float* Wpost2 = (const float*)d_in[12];
    const float* bpost2 = (const float*)d_in[13];
    const float* Wlin2  = (const float*)d_in[14];
    const float* blin2  = (const float*)d_in[15];
    const float* bn2g   = (const float*)d_in[16];
    const float* bn2b   = (const float*)d_in[17];
    float* out = (float*)d_out;
    (void)bpost1; (void)blin1; (void)bpre2; (void)bpost2; (void)blin2;  // cancel in BN

    char* ws = (char*)d_ws;
    size_t off = 0;
    auto alloc = [&](size_t bytes) { void* p = ws + off; off += (bytes + 255) & ~(size_t)255; return p; };
    int*    nbr  = (int*)   alloc((size_t)NN*7*4);
    float2* part = (float2*)alloc((size_t)NN*28*8);
    float* u1    = (float*)alloc((size_t)NN*32*4);
    float* v1    = (float*)alloc((size_t)NN*32*4);
    float* y1    = (float*)alloc((size_t)NN*64*4);
    unsigned short* v2 = (unsigned short*)alloc((size_t)NN*256*2);
    float* y2    = (float*)alloc((size_t)NN*128*4);
    unsigned short* Wf1p = (unsigned short*)alloc(4096*2);
    unsigned short* Wf1l = (unsigned short*)alloc(4096*2);
    unsigned short* Wfv = (unsigned short*)alloc(16384*2);
    unsigned short* Wfu = (unsigned short*)alloc(8192*2);
    unsigned short* Wfp = (unsigned short*)alloc(40960*2);
    unsigned short* Wfl = (unsigned short*)alloc(16384*2);
    float* P1s   = (float*)alloc(1024*64*4);
    float* P1q   = (float*)alloc(1024*64*4);
    float* A1s   = (float*)alloc(64*64*4);
    float* A1q   = (float*)alloc(64*64*4);
    float* sc1   = (float*)alloc(64*4);
    float* sh1   = (float*)alloc(64*4);
    float* P2s   = (float*)alloc(1024*128*4);
    float* P2q   = (float*)alloc(1024*128*4);
    float* A2s   = (float*)alloc(64*128*4);
    float* A2q   = (float*)alloc(64*128*4);
    float* sc2   = (float*)alloc(128*4);
    float* sh2   = (float*)alloc(128*4);
    float* Pp    = (float*)alloc(1024*128*4);

    prep_kernel<<<128, 256, 0, stream>>>(Wpost1, Wpost2, Wpre2, Wlin2, Wlin1,
                                         Wf1p, Wf1l, Wfv, Wfu, Wfp, Wfl);
    knn_part_kernel<<<NGRAPH*8, 256, 0, stream>>>(pos, part);
    knn_merge_kernel<<<NN/256, 256, 0, stream>>>(part, nbr);
    a1_kernel<<<NN/8, 256, 0, stream>>>(x, Wpre1, bpre1, u1, v1);
    b1_kernel<<<NN/16, 256, 0, stream>>>(x, nbr, u1, v1, Wf1p, Wf1l, y1);
    bn_stats_kernel<64><<<1024, 256, 0, stream>>>(y1, P1s, P1q);
    finA_kernel<64><<<64, 64, 0, stream>>>(P1s, P1q, A1s, A1q);
    fin_kernel<64><<<1, 64, 0, stream>>>(A1s, A1q, bn1g, bn1b, sc1, sh1);
    a2_kernel<<<NN/64, 256, 0, stream>>>(y1, sc1, sh1, Wfv, v2);
    b2_kernel<<<NN/16, 256, 0, stream>>>(nbr, y1, sc1, sh1, v2, Wfu, Wfp, Wfl, y2);
    bn_stats_kernel<128><<<1024, 256, 0, stream>>>(y2, P2s, P2q);
    finA_kernel<128><<<64, 128, 0, stream>>>(P2s, P2q, A2s, A2q);
    fin_kernel<128><<<1, 128, 0, stream>>>(A2s, A2q, bn2g, bn2b, sc2, sh2);
    pool_part_kernel<<<1024, 128, 0, stream>>>(y2, sc2, sh2, Pp);
    pool_fin_kernel<<<NGRAPH, 128, 0, stream>>>(Pp, out);
}

// Round 18
// 170.219 us; speedup vs baseline: 1.0822x; 1.0822x over previous
//
#include <hip/hip_runtime.h>
#include <math.h>

// PNANet on MI355X, round 18:
//  * REVERT b2 to round-16 (LDS-staged agg, 16B gathers) — round-17 registerization
//    removed the LDS latency-decoupling and regressed 45->55us.
//  * y2 stored f16: halves y2 write + 2x read traffic (BN2 stats + pool read f16,
//    accumulate fp32). ~50MB saved.

#define NGRAPH 128
#define NPG    512
#define NN     (NGRAPH*NPG)   // 65536
#define KNB    7

constexpr double AVG_DEG_LOG_D = 2.0239670479173344;  // (100*ln6+200*ln7+700*ln8)/1000
constexpr double LOG8_D        = 2.0794415416798357;

typedef _Float16 f16x8 __attribute__((ext_vector_type(8)));
typedef _Float16 h2    __attribute__((ext_vector_type(2)));
typedef float    f32x4 __attribute__((ext_vector_type(4)));

__device__ __forceinline__ unsigned short f2h(float x) {
    _Float16 h = (_Float16)x;
    return __builtin_bit_cast(unsigned short, h);
}
__device__ __forceinline__ float h2f(unsigned short u) {
    return (float)__builtin_bit_cast(_Float16, u);
}

// ---------------------------------------------------------------- weight prep
__global__ __launch_bounds__(256) void prep_kernel(
    const float* __restrict__ Wpost1, const float* __restrict__ Wpost2,
    const float* __restrict__ Wpre2,  const float* __restrict__ Wlin2,
    const float* __restrict__ Wlin1,
    unsigned short* __restrict__ Wf1p, unsigned short* __restrict__ Wf1l,
    unsigned short* __restrict__ Wfv, unsigned short* __restrict__ Wfu,
    unsigned short* __restrict__ Wfp, unsigned short* __restrict__ Wfl)
{
    const float AMP = (float)(LOG8_D / AVG_DEG_LOG_D);
    const float ATT = (float)(AVG_DEG_LOG_D / LOG8_D);
    for (int i = blockIdx.x*256 + threadIdx.x; i < 90112; i += gridDim.x*256) {
        if (i < 4096) {
            // Wf1p: [t][kk<2][lane<64][j<8]
            int t = i >> 10, kk = (i >> 9) & 1, lane = (i >> 3) & 63, j = i & 7;
            int k = kk*32 + ((lane >> 4) << 3) + j;
            int col = lane & 15;
            float val;
            if (k < 8)       val = Wpost1[(t*104 + k)*16 + col];
            else if (k < 40) {
                int g2 = k - 8;
                val = Wpost1[(t*104 +  8 + g2)*16 + col]
                    + AMP*Wpost1[(t*104 + 40 + g2)*16 + col]
                    + ATT*Wpost1[(t*104 + 72 + g2)*16 + col];
            } else val = 0.f;
            Wf1p[i] = f2h(val);
        } else if (i < 8192) {
            // Wf1l: [kk<2][tile<4][lane<64][j<8]
            int jj = i - 4096;
            int kk = jj >> 11, tile = (jj >> 9) & 3, lane = (jj >> 3) & 63, j = jj & 7;
            int k = kk*32 + ((lane >> 4) << 3) + j;
            int col = tile*16 + (lane & 15);
            Wf1l[jj] = f2h(Wlin1[k*64 + col]);
        } else if (i < 24576) {
            // Wfv: [kk<2][ct<16][lane<64][j<8] f16
            int jj = i - 8192;
            int kk = jj >> 13, ct = (jj >> 9) & 15, lane = (jj >> 3) & 63, jf = jj & 7;
            int k   = kk*32 + ((lane >> 4) << 3) + jf;
            int col = ct*16 + (lane & 15);
            int t = col >> 6, f = col & 63;
            Wfv[jj] = f2h(Wpre2[(t*128 + 64 + k)*64 + f]);
        } else if (i < 32768) {
            // Wfu_fold: [t][kk<2][c<2][lane<64][j<8]
            int jj = i - 24576;
            int t = jj >> 11, kk = (jj >> 10) & 1, c = (jj >> 9) & 1, lane = (jj >> 3) & 63, jf = jj & 7;
            int k   = kk*32 + ((lane >> 4) << 3) + jf;
            int col = c*16 + (lane & 15);
            float acc = 0.f;
            for (int f = 0; f < 64; ++f) {
                float wu = 0.f;
#pragma unroll
                for (int s = 0; s < 3; ++s) {
                    int g2 = s*64 + f;
                    wu += Wpost2[(t*832 +  64 + g2)*32 + col]
                        + AMP*Wpost2[(t*832 + 320 + g2)*32 + col]
                        + ATT*Wpost2[(t*832 + 576 + g2)*32 + col];
                }
                acc += Wpre2[(t*128 + k)*64 + f] * wu;
            }
            Wfu[jj] = f2h(acc);
        } else if (i < 73728) {
            // Wfrag_post: [t][kk<10][c<2][lane<64][j<8], f16
            int jj = i - 32768;
            int t = jj / 10240, r = jj % 10240;
            int kk = r / 1024, r2 = r % 1024;
            int c = r2 >> 9, lane = (r2 >> 3) & 63, jf = r2 & 7;
            int G   = kk*32 + ((lane >> 4) << 3) + jf;
            int col = c*16 + (lane & 15);
            float val;
            if (G < 64) val = Wpost2[(t*832 + G)*32 + col];
            else {
                int g2 = G - 64;
                val = Wpost2[(t*832 +  64 + g2)*32 + col]
                    + AMP*Wpost2[(t*832 + 320 + g2)*32 + col]
                    + ATT*Wpost2[(t*832 + 576 + g2)*32 + col];
            }
            Wfp[jj] = f2h(val);
        } else {
            // Wfrag_lin: [kk<4][tile<8][lane<64][j<8], f16
            int jj = i - 73728;
            int kk = jj / 4096, r = jj % 4096;
            int tile = r >> 9, lane = (r >> 3) & 63, jf = r & 7;
            int k   = kk*32 + ((lane >> 4) << 3) + jf;
            int col = tile*16 + (lane & 15);
            Wfl[jj] = f2h(Wlin2[k*128 + col]);
        }
    }
}

// ---------------------------------------------------------------- kNN part
__global__ __launch_bounds__(256) void knn_part_kernel(const float* __restrict__ pos, float2* __restrict__ part)
{
    __shared__ float4 cposS[128];
    const int b = blockIdx.x;
    const int g = b >> 3, h = (b >> 2) & 1, q = b & 3;
    const int gb = g * NPG;
    const int cbase = q * 128;
    if (threadIdx.x < 128) {
        int j = cbase + threadIdx.x;
        cposS[threadIdx.x] = make_float4(pos[(gb+j)*3+0], pos[(gb+j)*3+1], pos[(gb+j)*3+2], 0.f);
    }
    __syncthreads();
    const int i = h*256 + threadIdx.x;
    const float px = pos[(gb+i)*3+0], py = pos[(gb+i)*3+1], pz = pos[(gb+i)*3+2];
    float bd[KNB]; int bi[KNB];
#pragma unroll
    for (int e = 0; e < KNB; ++e) { bd[e] = 3.0e38f; bi[e] = -1; }
#pragma unroll 4
    for (int j = 0; j < 128; ++j) {
        float4 pj = cposS[j];
        float dx = px - pj.x, dy = py - pj.y, dz = pz - pj.z;
        float d2 = __fadd_rn(__fadd_rn(__fmul_rn(dx,dx), __fmul_rn(dy,dy)), __fmul_rn(dz,dz));
        if (cbase + j == i) d2 = __builtin_inff();
        bool cmp[KNB];
#pragma unroll
        for (int e = 0; e < KNB; ++e) cmp[e] = d2 < bd[e];
#pragma unroll
        for (int e = KNB-1; e >= 1; --e) {
            bd[e] = cmp[e-1] ? bd[e-1] : (cmp[e] ? d2 : bd[e]);
            bi[e] = cmp[e-1] ? bi[e-1] : (cmp[e] ? cbase + j : bi[e]);
        }
        bd[0] = cmp[0] ? d2 : bd[0];
        bi[0] = cmp[0] ? cbase + j : bi[0];
    }
    float2* dst = &part[((size_t)(g*NPG + i)*4 + q)*KNB];
#pragma unroll
    for (int e = 0; e < KNB; ++e) dst[e] = make_float2(bd[e], __int_as_float(bi[e]));
}

// ---------------------------------------------------------------- kNN merge
__global__ __launch_bounds__(256) void knn_merge_kernel(const float2* __restrict__ part, int* __restrict__ nbr)
{
    const int n = blockIdx.x*256 + threadIdx.x;
    const float4* p4 = (const float4*)&part[(size_t)n*28];
    float bd[KNB]; int bi[KNB];
#pragma unroll
    for (int e = 0; e < KNB; ++e) { bd[e] = 3.0e38f; bi[e] = -1; }
#pragma unroll
    for (int m4 = 0; m4 < 14; ++m4) {
        float4 pr = p4[m4];
#pragma unroll
        for (int half = 0; half < 2; ++half) {
            float d2  = half ? pr.z : pr.x;
            int   idx = __float_as_int(half ? pr.w : pr.y);
            bool cmp[KNB];
#pragma unroll
            for (int e = 0; e < KNB; ++e) cmp[e] = d2 < bd[e];
#pragma unroll
            for (int e = KNB-1; e >= 1; --e) {
                bd[e] = cmp[e-1] ? bd[e-1] : (cmp[e] ? d2 : bd[e]);
                bi[e] = cmp[e-1] ? bi[e-1] : (cmp[e] ? idx : bi[e]);
            }
            bd[0] = cmp[0] ? d2 : bd[0];
            bi[0] = cmp[0] ? idx : bi[0];
        }
    }
    const int gb = n & ~(NPG-1);
#pragma unroll
    for (int e = 0; e < KNB; ++e) nbr[n*KNB + e] = gb + bi[e];
}

// ---------------------------------------------------------------- layer1: u1,v1 [N,32]
__global__ __launch_bounds__(256) void a1_kernel(
    const float* __restrict__ x, const float* __restrict__ Wpre1, const float* __restrict__ bpre1,
    float* __restrict__ u1, float* __restrict__ v1)
{
    __shared__ float wS[512];
    __shared__ float bS[32];
    const int tid = threadIdx.x;
    wS[tid] = Wpre1[tid]; wS[tid+256] = Wpre1[tid+256];
    if (tid < 32) bS[tid] = bpre1[tid];
    __syncthreads();
    const int n  = blockIdx.x*8 + (tid>>5);
    const int tf = tid & 31;
    const int t = tf >> 3, f = tf & 7;
    float u = bS[tf], v = 0.f;
#pragma unroll
    for (int e = 0; e < 8; ++e) {
        float xv = x[n*8+e];
        u += xv * wS[(t*16 + e)*8 + f];
        v += xv * wS[(t*16 + 8 + e)*8 + f];
    }
    u1[n*32+tf] = u;
    v1[n*32+tf] = v;
}

// ---------------------------------------------------------------- layer1 fused (MFMA f16)
__global__ __launch_bounds__(256) void b1_kernel(
    const float* __restrict__ x, const int* __restrict__ nbr,
    const float* __restrict__ u1, const float* __restrict__ v1,
    const unsigned short* __restrict__ Wf1p, const unsigned short* __restrict__ Wf1l,
    float* __restrict__ y1)
{
    __shared__ int nbrsS[112];
    __shared__ __align__(16) unsigned short actS[64*72];
    __shared__ __align__(16) unsigned short postS[16*72];
    const int tid  = threadIdx.x;
    const int base = blockIdx.x * 16;
    if (tid < 112) nbrsS[tid] = nbr[base*7 + tid];
    for (int i = tid; i < 384; i += 256) {
        int r = i / 6, gq = i - 6*r;
        *(ushort4*)&actS[r*72 + 40 + gq*4] = make_ushort4(0,0,0,0);
    }
#pragma unroll
    for (int it = 0; it < 2; ++it) {
        int i = tid + it*256;
        int n = i >> 5, r2 = i & 31, t = r2 >> 3, f = r2 & 7;
        actS[(n*4 + t)*72 + f] = f2h(x[(base+n)*8 + f]);
    }
    __syncthreads();
    {
        const int n = tid >> 4, cp = tid & 15;
        const int tf0 = cp*2, t = tf0 >> 3, f0 = tf0 & 7;
        float2 uu = *(const float2*)&u1[(base+n)*32 + tf0];
        float s0=0.f,s1=0.f,q0=0.f,q1=0.f;
        float mn0=3e38f,mn1=3e38f,mx0=-3e38f,mx1=-3e38f;
#pragma unroll
        for (int e = 0; e < 7; ++e) {
            float2 vv = *(const float2*)&v1[nbrsS[n*7+e]*32 + tf0];
            s0 += vv.x; q0 += vv.x*vv.x; mn0 = fminf(mn0, vv.x); mx0 = fmaxf(mx0, vv.x);
            s1 += vv.y; q1 += vv.y*vv.y; mn1 = fminf(mn1, vv.y); mx1 = fmaxf(mx1, vv.y);
        }
        float me0 = s0*(1.f/7.f), me1 = s1*(1.f/7.f);
        float sd0 = sqrtf(fmaxf(q0*(1.f/7.f) - me0*me0, 0.f) + 1e-5f);
        float sd1 = sqrtf(fmaxf(q1*(1.f/7.f) - me1*me1, 0.f) + 1e-5f);
        const int row = (n*4 + t)*72;
        ushort2 w_;
        w_.x = f2h(uu.x + me0); w_.y = f2h(uu.y + me1); *(ushort2*)&actS[row +  8 + f0] = w_;
        w_.x = f2h(uu.x + mn0); w_.y = f2h(uu.y + mn1); *(ushort2*)&actS[row + 16 + f0] = w_;
        w_.x = f2h(uu.x + mx0); w_.y = f2h(uu.y + mx1); *(ushort2*)&actS[row + 24 + f0] = w_;
        w_.x = f2h(sd0);        w_.y = f2h(sd1);        *(ushort2*)&actS[row + 32 + f0] = w_;
    }
    __syncthreads();
    const int l = tid & 63, w = tid >> 6;
    const int lr = l & 15, lk = l >> 4;
    f32x4 acc = {0.f,0.f,0.f,0.f};
    {
        const f16x8* WB = (const f16x8*)Wf1p;
#pragma unroll
        for (int kk = 0; kk < 2; ++kk) {
            f16x8 a = *(const f16x8*)&actS[(lr*4 + w)*72 + kk*32 + lk*8];
            f16x8 b = WB[(w*2 + kk)*64 + l];
            acc = __builtin_amdgcn_mfma_f32_16x16x32_f16(a, b, acc, 0, 0, 0);
        }
    }
#pragma unroll
    for (int j = 0; j < 4; ++j)
        postS[(lk*4 + j)*72 + w*16 + lr] = f2h(acc[j]);
    __syncthreads();
    f32x4 d = {0.f,0.f,0.f,0.f};
    {
        const f16x8* WB = (const f16x8*)Wf1l;
#pragma unroll
        for (int kk = 0; kk < 2; ++kk) {
            f16x8 a = *(const f16x8*)&postS[lr*72 + kk*32 + lk*8];
            f16x8 b = WB[(kk*4 + w)*64 + l];
            d = __builtin_amdgcn_mfma_f32_16x16x32_f16(a, b, d, 0, 0, 0);
        }
    }
#pragma unroll
    for (int j = 0; j < 4; ++j)
        y1[(base + lk*4 + j)*64 + w*16 + lr] = d[j];
}

// ---------------------------------------------------------------- BN stats fp32 input (y1)
template<int C>
__global__ __launch_bounds__(256) void bn_stats_kernel(
    const float* __restrict__ y, float* __restrict__ Ps, float* __restrict__ Pq)
{
    constexpr int IT     = (NN/1024)*(C/4)/256;
    constexpr int GROUPS = C/4;
    constexpr int REPS   = 256/GROUPS;
    const int tid = threadIdx.x;
    const float4* y4 = (const float4*)y + (size_t)blockIdx.x*256*IT;
    float4 s = make_float4(0.f,0.f,0.f,0.f), q = make_float4(0.f,0.f,0.f,0.f);
#pragma unroll
    for (int it = 0; it < IT; ++it) {
        float4 v = y4[it*256 + tid];
        s.x += v.x; s.y += v.y; s.z += v.z; s.w += v.w;
        q.x += v.x*v.x; q.y += v.y*v.y; q.z += v.z*v.z; q.w += v.w*v.w;
    }
    __shared__ float4 sS[256], qS[256];
    sS[tid] = s; qS[tid] = q;
    __syncthreads();
#pragma unroll
    for (int step = REPS/2; step >= 1; step >>= 1) {
        if (tid < step*GROUPS) {
            float4 s2 = sS[tid + step*GROUPS], q2 = qS[tid + step*GROUPS];
            float4 ss = sS[tid], qq = qS[tid];
            ss.x += s2.x; ss.y += s2.y; ss.z += s2.z; ss.w += s2.w;
            qq.x += q2.x; qq.y += q2.y; qq.z += q2.z; qq.w += q2.w;
            sS[tid] = ss; qS[tid] = qq;
        }
        __syncthreads();
    }
    if (tid < GROUPS) {
        ((float4*)&Ps[(size_t)blockIdx.x*C])[tid] = sS[tid];
        ((float4*)&Pq[(size_t)blockIdx.x*C])[tid] = qS[tid];
    }
}

// ---------------------------------------------------------------- BN stats f16 input (y2h), C=128
__global__ __launch_bounds__(256) void bn_stats_h_kernel(
    const unsigned short* __restrict__ yh, float* __restrict__ Ps, float* __restrict__ Pq)
{
    const int tid = threadIdx.x;
    const int rg = tid >> 4, cgg = tid & 15;     // 16 rows x 16 col-groups(8)
    float s[8], q[8];
#pragma unroll
    for (int j = 0; j < 8; ++j) { s[j] = 0.f; q[j] = 0.f; }
    const size_t rowBase = (size_t)blockIdx.x * 64;
#pragma unroll
    for (int it = 0; it < 4; ++it) {
        const int r = it*16 + rg;
        uint4 vv = *(const uint4*)&yh[(rowBase + r)*128 + cgg*8];
        unsigned wds[4] = {vv.x, vv.y, vv.z, vv.w};
#pragma unroll
        for (int p = 0; p < 4; ++p) {
            h2 v = __builtin_bit_cast(h2, wds[p]);
            float f0 = (float)v[0], f1 = (float)v[1];
            s[p*2]   += f0; q[p*2]   += f0*f0;
            s[p*2+1] += f1; q[p*2+1] += f1*f1;
        }
    }
    __shared__ float sS[256*8], qS[256*8];
#pragma unroll
    for (int j = 0; j < 8; ++j) { sS[tid*8+j] = s[j]; qS[tid*8+j] = q[j]; }
    __syncthreads();
#pragma unroll
    for (int step = 8; step >= 1; step >>= 1) {
        if (rg < step) {
            const int o = (tid + step*16)*8;
#pragma unroll
            for (int j = 0; j < 8; ++j) { sS[tid*8+j] += sS[o+j]; qS[tid*8+j] += qS[o+j]; }
        }
        __syncthreads();
    }
    if (rg == 0) {
#pragma unroll
        for (int j = 0; j < 8; ++j) {
            Ps[(size_t)blockIdx.x*128 + cgg*8 + j] = sS[tid*8+j];
            Pq[(size_t)blockIdx.x*128 + cgg*8 + j] = qS[tid*8+j];
        }
    }
}

// ---------------------------------------------------------------- finA: 64 blocks, sum 16 partial-rows
template<int C>
__global__ __launch_bounds__(C) void finA_kernel(
    const float* __restrict__ Ps, const float* __restrict__ Pq,
    float* __restrict__ As, float* __restrict__ Aq)
{
    const int c = threadIdx.x, b = blockIdx.x;
    float s = 0.f, q = 0.f;
#pragma unroll
    for (int i = 0; i < 16; ++i) {
        s += Ps[(b*16 + i)*C + c];
        q += Pq[(b*16 + i)*C + c];
    }
    As[b*C + c] = s;
    Aq[b*C + c] = q;
}

// ---------------------------------------------------------------- finalize BN -> scale/shift
template<int C>
__global__ __launch_bounds__(C) void fin_kernel(
    const float* __restrict__ As, const float* __restrict__ Aq,
    const float* __restrict__ g, const float* __restrict__ b,
    float* __restrict__ scO, float* __restrict__ shO)
{
    const int c = threadIdx.x;
    float s = 0.f, q = 0.f;
#pragma unroll 8
    for (int i = 0; i < 64; ++i) { s += As[i*C + c]; q += Aq[i*C + c]; }
    const float inv = 1.f/(float)NN;
    float mu  = s*inv;
    float var = q*inv - mu*mu;
    float sc  = g[c]*rsqrtf(var + 1e-5f);
    scO[c] = sc;
    shO[c] = b[c] - mu*sc;
}

// ---------------------------------------------------------------- layer2 pre (MFMA f16): v2 [N][256] f16
__global__ __launch_bounds__(256) void a2_kernel(
    const float* __restrict__ y1raw, const float* __restrict__ sc1, const float* __restrict__ sh1,
    const unsigned short* __restrict__ Wfv,
    unsigned short* __restrict__ v2)
{
    __shared__ __align__(16) unsigned short a1S[64*72];
    const int tid  = threadIdx.x;
    const int base = blockIdx.x * 64;
#pragma unroll
    for (int it = 0; it < 4; ++it) {
        int i = tid + it*256;
        float4 vv = ((const float4*)y1raw)[blockIdx.x*1024 + i];
        int n = i >> 4, c0 = (i & 15)*4;
        float c_[4] = {vv.x, vv.y, vv.z, vv.w};
#pragma unroll
        for (int j = 0; j < 4; ++j) {
            int c = c0 + j;
            a1S[n*72 + c] = f2h(fmaxf(c_[j]*sc1[c] + sh1[c], 0.f));
        }
    }
    __syncthreads();
    const int l = tid & 63, w = tid >> 6;
    const int lr = l & 15, lk = l >> 4;
    const f16x8 a0  = *(const f16x8*)&a1S[(w*16 + lr)*72 +      lk*8];
    const f16x8 a1f = *(const f16x8*)&a1S[(w*16 + lr)*72 + 32 + lk*8];
    const f16x8* WB = (const f16x8*)Wfv;
#pragma unroll 4
    for (int ct = 0; ct < 16; ++ct) {
        f32x4 acc = {0.f,0.f,0.f,0.f};
        f16x8 b0 = WB[ct*64 + l];
        f16x8 b1 = WB[(16 + ct)*64 + l];
        acc = __builtin_amdgcn_mfma_f32_16x16x32_f16(a0,  b0, acc, 0, 0, 0);
        acc = __builtin_amdgcn_mfma_f32_16x16x32_f16(a1f, b1, acc, 0, 0, 0);
        const int col = ct*16 + lr;
#pragma unroll
        for (int j = 0; j < 4; ++j)
            v2[(size_t)(base + w*16 + lk*4 + j)*256 + col] = f2h(acc[j]);
    }
}

// ---------------------------------------------------------------- layer2 fused (MFMA f16): agg + post(+ufold) + lin -> y2h
__global__ __launch_bounds__(256) void b2_kernel(
    const int* __restrict__ nbr, const float* __restrict__ y1raw,
    const float* __restrict__ sc1, const float* __restrict__ sh1,
    const unsigned short* __restrict__ v2,
    const unsigned short* __restrict__ Wfu,
    const unsigned short* __restrict__ Wfp, const unsigned short* __restrict__ Wfl,
    unsigned short* __restrict__ y2h)
{
    __shared__ int nbrsS[112];
    __shared__ __align__(16) unsigned short a1S[16*72];
    __shared__ __align__(16) unsigned short aggS[64*264];
    __shared__ __align__(16) unsigned short postS[16*136];

    const int tid = threadIdx.x;
    const int ob   = blockIdx.x;
    const int xcd  = ob & 7, slot = ob >> 3;
    const int gph  = ((slot >> 5) << 3) + xcd;
    const int sub  = slot & 31;
    const int base = gph*NPG + sub*16;

    if (tid < 112) nbrsS[tid] = nbr[base*7 + tid];
    for (int i = tid; i < 1024; i += 256) {
        int c = i & 63, n = i >> 6;
        float a = fmaxf(y1raw[base*64 + i]*sc1[c] + sh1[c], 0.f);
        a1S[n*72 + c] = f2h(a);
    }
    __syncthreads();
    // ---- aggregation: 16B (ushort8) gathers, 8 cols/thread, 8 node-slots x 2 iters
    {
        const int ns = tid >> 5, cg = tid & 31;
        const int t = cg >> 3, f0 = (cg & 7) * 8;
        const h2 inv7 = { (_Float16)(1.f/7.f), (_Float16)(1.f/7.f) };
#pragma unroll
        for (int it = 0; it < 2; ++it) {
            const int ln = it*8 + ns;
            h2 z = { (_Float16)0.f, (_Float16)0.f };
            h2 s[4]  = {z,z,z,z};
            h2 q[4]  = {z,z,z,z};
            h2 mn[4], mx[4];
#pragma unroll
            for (int p = 0; p < 4; ++p) {
                mn[p] = h2{ (_Float16)65504.f, (_Float16)65504.f };
                mx[p] = h2{ (_Float16)-65504.f, (_Float16)-65504.f };
            }
#pragma unroll
            for (int e = 0; e < 7; ++e) {
                uint4 vv = *(const uint4*)&v2[(size_t)nbrsS[ln*7+e]*256 + cg*8];
                unsigned vw[4] = {vv.x, vv.y, vv.z, vv.w};
#pragma unroll
                for (int p = 0; p < 4; ++p) {
                    h2 v = __builtin_bit_cast(h2, vw[p]);
                    s[p] += v;
                    q[p] += v*v;
                    mn[p] = __builtin_elementwise_min(mn[p], v);
                    mx[p] = __builtin_elementwise_max(mx[p], v);
                }
            }
            unsigned meW[4], mnW[4], mxW[4], sdW[4];
#pragma unroll
            for (int p = 0; p < 4; ++p) {
                h2 me = s[p]*inv7;
                float m0 = (float)me[0], m1 = (float)me[1];
                float sd0 = sqrtf(fmaxf(fmaf((float)q[p][0], 1.f/7.f, -m0*m0), 0.f) + 1e-5f);
                float sd1 = sqrtf(fmaxf(fmaf((float)q[p][1], 1.f/7.f, -m1*m1), 0.f) + 1e-5f);
                h2 sd = { (_Float16)sd0, (_Float16)sd1 };
                meW[p] = __builtin_bit_cast(unsigned, me);
                mnW[p] = __builtin_bit_cast(unsigned, mn[p]);
                mxW[p] = __builtin_bit_cast(unsigned, mx[p]);
                sdW[p] = __builtin_bit_cast(unsigned, sd);
            }
            const int ro = (t*16 + ln)*264 + f0;
            *(uint4*)&aggS[ro      ] = make_uint4(meW[0], meW[1], meW[2], meW[3]);
            *(uint4*)&aggS[ro +  64] = make_uint4(mnW[0], mnW[1], mnW[2], mnW[3]);
            *(uint4*)&aggS[ro + 128] = make_uint4(mxW[0], mxW[1], mxW[2], mxW[3]);
            *(uint4*)&aggS[ro + 192] = make_uint4(sdW[0], sdW[1], sdW[2], sdW[3]);
        }
    }
    __syncthreads();
    const int l = tid & 63, w = tid >> 6;
    const int lr = l & 15, lk = l >> 4;
    // ---- post GEMM (tower w): 2 a1-direct + 2 a1-ufold + 8 agg chunks
    f32x4 acc0 = {0.f,0.f,0.f,0.f}, acc1 = {0.f,0.f,0.f,0.f};
    {
        const f16x8* WP = (const f16x8*)Wfp;
        const f16x8* WU = (const f16x8*)Wfu;
#pragma unroll
        for (int kk = 0; kk < 12; ++kk) {
            f16x8 a, b0, b1;
            if (kk < 2) {
                a  = *(const f16x8*)&a1S[lr*72 + kk*32 + lk*8];
                b0 = WP[((w*10 + kk)*2 + 0)*64 + l];
                b1 = WP[((w*10 + kk)*2 + 1)*64 + l];
            } else if (kk < 4) {
                a  = *(const f16x8*)&a1S[lr*72 + (kk-2)*32 + lk*8];
                b0 = WU[((w*2 + (kk-2))*2 + 0)*64 + l];
                b1 = WU[((w*2 + (kk-2))*2 + 1)*64 + l];
            } else {
                a  = *(const f16x8*)&aggS[(w*16 + lr)*264 + (kk-4)*32 + lk*8];
                b0 = WP[((w*10 + (kk-2))*2 + 0)*64 + l];
                b1 = WP[((w*10 + (kk-2))*2 + 1)*64 + l];
            }
            acc0 = __builtin_amdgcn_mfma_f32_16x16x32_f16(a, b0, acc0, 0, 0, 0);
            acc1 = __builtin_amdgcn_mfma_f32_16x16x32_f16(a, b1, acc1, 0, 0, 0);
        }
    }
#pragma unroll
    for (int j = 0; j < 4; ++j) {
        const int row = lk*4 + j;
        postS[row*136 + w*32 +      lr] = f2h(acc0[j]);
        postS[row*136 + w*32 + 16 + lr] = f2h(acc1[j]);
    }
    __syncthreads();
    // ---- lin GEMM (cols 32w..32w+31): K=128; bias cancels in BN2
    f32x4 d0 = {0.f,0.f,0.f,0.f}, d1 = {0.f,0.f,0.f,0.f};
    {
        const f16x8* WB = (const f16x8*)Wfl;
#pragma unroll
        for (int kk = 0; kk < 4; ++kk) {
            f16x8 a = *(const f16x8*)&postS[lr*136 + kk*32 + lk*8];
            f16x8 b0 = WB[(kk*8 + 2*w + 0)*64 + l];
            f16x8 b1 = WB[(kk*8 + 2*w + 1)*64 + l];
            d0 = __builtin_amdgcn_mfma_f32_16x16x32_f16(a, b0, d0, 0, 0, 0);
            d1 = __builtin_amdgcn_mfma_f32_16x16x32_f16(a, b1, d1, 0, 0, 0);
        }
    }
#pragma unroll
    for (int j = 0; j < 4; ++j) {
        const int row = lk*4 + j;
        y2h[(size_t)(base + row)*128 + w*32 +      lr] = f2h(d0[j]);
        y2h[(size_t)(base + row)*128 + w*32 + 16 + lr] = f2h(d1[j]);
    }
}

// ---------------------------------------------------------------- pool part (f16 y2): BN2+relu+64-row partials
__global__ __launch_bounds__(128) void pool_part_h_kernel(
    const unsigned short* __restrict__ y2h, const float* __restrict__ sc2, const float* __restrict__ sh2,
    float* __restrict__ Pp)
{
    const int c = threadIdx.x;
    const int b = blockIdx.x;
    const float sc = sc2[c];
    const float sh = sh2[c];
    float acc = 0.f;
    const size_t base = (size_t)b*64*128 + c;
#pragma unroll 4
    for (int i = 0; i < 64; ++i)
        acc += fmaxf(h2f(y2h[base + (size_t)i*128])*sc + sh, 0.f);
    Pp[b*128 + c] = acc;
}

// ---------------------------------------------------------------- pool finalize
__global__ __launch_bounds__(128) void pool_fin_kernel(
    const float* __restrict__ Pp, float* __restrict__ out)
{
    const int c = threadIdx.x, g = blockIdx.x;
    float acc = 0.f;
#pragma unroll
    for (int i = 0; i < 8; ++i) acc += Pp[(g*8 + i)*128 + c];
    out[g*128 + c] = acc * (1.f/(float)NPG);
}

// ---------------------------------------------------------------- launcher
extern "C" void kernel_launch(void* const* d_in, const int* in_sizes, int n_in,
                              void* d_out, int out_size, void* d_ws, size_t ws_size,
                              hipStream_t stream)
{
    const float* x      = (const float*)d_in[0];
    const float* pos    = (const float*)d_in[1];
    const float* Wpre1  = (const float*)d_in[2];
    const float* bpre1  = (const float*)d_in[3];
    const float* Wpost1 = (const float*)d_in[4];
    const float* bpost1 = (const float*)d_in[5];
    const float* Wlin1  = (const float*)d_in[6];
    const float* blin1  = (const float*)d_in[7];
    const float* bn1g   = (const float*)d_in[8];
    const float* bn1b   = (const float*)d_in[9];
    const float* Wpre2  = (const float*)d_in[10];
    const float* bpre2  = (const float*)d_in[11];
    const float* Wpost2 = (const float*)d_in[12];
    const float* bpost2 = (const float*)d_in[13];
    const float* Wlin2  = (const float*)d_in[14];
    const float* blin2  = (const float*)d_in[15];
    const float* bn2g   = (const float*)d_in[16];
    const float* bn2b   = (const float*)d_in[17];
    float* out = (float*)d_out;
    (void)bpost1; (void)blin1; (void)bpre2; (void)bpost2; (void)blin2;  // cancel in BN

    char* ws = (char*)d_ws;
    size_t off = 0;
    auto alloc = [&](size_t bytes) { void* p = ws + off; off += (bytes + 255) & ~(size_t)255; return p; };
    int*    nbr  = (int*)   alloc((size_t)NN*7*4);
    float2* part = (float2*)alloc((size_t)NN*28*8);
    float* u1    = (float*)alloc((size_t)NN*32*4);
    float* v1    = (float*)alloc((size_t)NN*32*4);
    float* y1    = (float*)alloc((size_t)NN*64*4);
    unsigned short* v2  = (unsigned short*)alloc((size_t)NN*256*2);
    unsigned short* y2h = (unsigned short*)alloc((size_t)NN*128*2);
    unsigned short* Wf1p = (unsigned short*)alloc(4096*2);
    unsigned short* Wf1l = (unsigned short*)alloc(4096*2);
    unsigned short* Wfv = (unsigned short*)alloc(16384*2);
    unsigned short* Wfu = (unsigned short*)alloc(8192*2);
    unsigned short* Wfp = (unsigned short*)alloc(40960*2);
    unsigned short* Wfl = (unsigned short*)alloc(16384*2);
    float* P1s   = (float*)alloc(1024*64*4);
    float* P1q   = (float*)alloc(1024*64*4);
    float* A1s   = (float*)alloc(64*64*4);
    float* A1q   = (float*)alloc(64*64*4);
    float* sc1   = (float*)alloc(64*4);
    float* sh1   = (float*)alloc(64*4);
    float* P2s   = (float*)alloc(1024*128*4);
    float* P2q   = (float*)alloc(1024*128*4);
    float* A2s   = (float*)alloc(64*128*4);
    float* A2q   = (float*)alloc(64*128*4);
    float* sc2   = (float*)alloc(128*4);
    float* sh2   = (float*)alloc(128*4);
    float* Pp    = (float*)alloc(1024*128*4);

    prep_kernel<<<128, 256, 0, stream>>>(Wpost1, Wpost2, Wpre2, Wlin2, Wlin1,
                                         Wf1p, Wf1l, Wfv, Wfu, Wfp, Wfl);
    knn_part_kernel<<<NGRAPH*8, 256, 0, stream>>>(pos, part);
    knn_merge_kernel<<<NN/256, 256, 0, stream>>>(part, nbr);
    a1_kernel<<<NN/8, 256, 0, stream>>>(x, Wpre1, bpre1, u1, v1);
    b1_kernel<<<NN/16, 256, 0, stream>>>(x, nbr, u1, v1, Wf1p, Wf1l, y1);
    bn_stats_kernel<64><<<1024, 256, 0, stream>>>(y1, P1s, P1q);
    finA_kernel<64><<<64, 64, 0, stream>>>(P1s, P1q, A1s, A1q);
    fin_kernel<64><<<1, 64, 0, stream>>>(A1s, A1q, bn1g, bn1b, sc1, sh1);
    a2_kernel<<<NN/64, 256, 0, stream>>>(y1, sc1, sh1, Wfv, v2);
    b2_kernel<<<NN/16, 256, 0, stream>>>(nbr, y1, sc1, sh1, v2, Wfu, Wfp, Wfl, y2h);
    bn_stats_h_kernel<<<1024, 256, 0, stream>>>(y2h, P2s, P2q);
    finA_kernel<128><<<64, 128, 0, stream>>>(P2s, P2q, A2s, A2q);
    fin_kernel<128><<<1, 128, 0, stream>>>(A2s, A2q, bn2g, bn2b, sc2, sh2);
    pool_part_h_kernel<<<1024, 128, 0, stream>>>(y2h, sc2, sh2, Pp);
    pool_fin_kernel<<<NGRAPH, 128, 0, stream>>>(Pp, out);
}

// Round 19
// 163.490 us; speedup vs baseline: 1.1268x; 1.0412x over previous
//
#include <hip/hip_runtime.h>
#include <math.h>

// PNANet on MI355X, round 19:
//  * b2: alias postS into aggS (+1 barrier) -> LDS 41->36.5KB -> 4 blocks/CU
//    (occupancy was LDS-capped at 3 blocks/CU = 34%).
//  * prep0: materialize Wusum once; prep's Wfu loop 6 loads/iter -> 2.
//  * rest identical to round 18.

#define NGRAPH 128
#define NPG    512
#define NN     (NGRAPH*NPG)   // 65536
#define KNB    7

constexpr double AVG_DEG_LOG_D = 2.0239670479173344;  // (100*ln6+200*ln7+700*ln8)/1000
constexpr double LOG8_D        = 2.0794415416798357;

typedef _Float16 f16x8 __attribute__((ext_vector_type(8)));
typedef _Float16 h2    __attribute__((ext_vector_type(2)));
typedef float    f32x4 __attribute__((ext_vector_type(4)));

__device__ __forceinline__ unsigned short f2h(float x) {
    _Float16 h = (_Float16)x;
    return __builtin_bit_cast(unsigned short, h);
}
__device__ __forceinline__ float h2f(unsigned short u) {
    return (float)__builtin_bit_cast(_Float16, u);
}

// ---------------------------------------------------------------- prep0: Wusum[t][f][col] = sum of 3 scaled Wpost2 rows
__global__ __launch_bounds__(256) void prep0_kernel(
    const float* __restrict__ Wpost2, float* __restrict__ Wusum)
{
    const float AMP = (float)(LOG8_D / AVG_DEG_LOG_D);
    const float ATT = (float)(AVG_DEG_LOG_D / LOG8_D);
    const int i = blockIdx.x*256 + threadIdx.x;       // 8192 = 4*64*32
    const int t = i >> 11, f = (i >> 5) & 63, col = i & 31;
    float wu = 0.f;
#pragma unroll
    for (int s = 0; s < 3; ++s) {
        int g2 = s*64 + f;
        wu += Wpost2[(t*832 +  64 + g2)*32 + col]
            + AMP*Wpost2[(t*832 + 320 + g2)*32 + col]
            + ATT*Wpost2[(t*832 + 576 + g2)*32 + col];
    }
    Wusum[i] = wu;
}

// ---------------------------------------------------------------- weight prep
__global__ __launch_bounds__(256) void prep_kernel(
    const float* __restrict__ Wpost1, const float* __restrict__ Wpost2,
    const float* __restrict__ Wpre2,  const float* __restrict__ Wlin2,
    const float* __restrict__ Wlin1,  const float* __restrict__ Wusum,
    unsigned short* __restrict__ Wf1p, unsigned short* __restrict__ Wf1l,
    unsigned short* __restrict__ Wfv, unsigned short* __restrict__ Wfu,
    unsigned short* __restrict__ Wfp, unsigned short* __restrict__ Wfl)
{
    const float AMP = (float)(LOG8_D / AVG_DEG_LOG_D);
    const float ATT = (float)(AVG_DEG_LOG_D / LOG8_D);
    for (int i = blockIdx.x*256 + threadIdx.x; i < 90112; i += gridDim.x*256) {
        if (i < 4096) {
            // Wf1p: [t][kk<2][lane<64][j<8]
            int t = i >> 10, kk = (i >> 9) & 1, lane = (i >> 3) & 63, j = i & 7;
            int k = kk*32 + ((lane >> 4) << 3) + j;
            int col = lane & 15;
            float val;
            if (k < 8)       val = Wpost1[(t*104 + k)*16 + col];
            else if (k < 40) {
                int g2 = k - 8;
                val = Wpost1[(t*104 +  8 + g2)*16 + col]
                    + AMP*Wpost1[(t*104 + 40 + g2)*16 + col]
                    + ATT*Wpost1[(t*104 + 72 + g2)*16 + col];
            } else val = 0.f;
            Wf1p[i] = f2h(val);
        } else if (i < 8192) {
            // Wf1l: [kk<2][tile<4][lane<64][j<8]
            int jj = i - 4096;
            int kk = jj >> 11, tile = (jj >> 9) & 3, lane = (jj >> 3) & 63, j = jj & 7;
            int k = kk*32 + ((lane >> 4) << 3) + j;
            int col = tile*16 + (lane & 15);
            Wf1l[jj] = f2h(Wlin1[k*64 + col]);
        } else if (i < 24576) {
            // Wfv: [kk<2][ct<16][lane<64][j<8] f16
            int jj = i - 8192;
            int kk = jj >> 13, ct = (jj >> 9) & 15, lane = (jj >> 3) & 63, jf = jj & 7;
            int k   = kk*32 + ((lane >> 4) << 3) + jf;
            int col = ct*16 + (lane & 15);
            int t = col >> 6, f = col & 63;
            Wfv[jj] = f2h(Wpre2[(t*128 + 64 + k)*64 + f]);
        } else if (i < 32768) {
            // Wfu_fold: [t][kk<2][c<2][lane<64][j<8] via Wusum
            int jj = i - 24576;
            int t = jj >> 11, kk = (jj >> 10) & 1, c = (jj >> 9) & 1, lane = (jj >> 3) & 63, jf = jj & 7;
            int k   = kk*32 + ((lane >> 4) << 3) + jf;
            int col = c*16 + (lane & 15);
            float acc = 0.f;
            for (int f = 0; f < 64; ++f)
                acc += Wpre2[(t*128 + k)*64 + f] * Wusum[(t*64 + f)*32 + col];
            Wfu[jj] = f2h(acc);
        } else if (i < 73728) {
            // Wfrag_post: [t][kk<10][c<2][lane<64][j<8], f16
            int jj = i - 32768;
            int t = jj / 10240, r = jj % 10240;
            int kk = r / 1024, r2 = r % 1024;
            int c = r2 >> 9, lane = (r2 >> 3) & 63, jf = r2 & 7;
            int G   = kk*32 + ((lane >> 4) << 3) + jf;
            int col = c*16 + (lane & 15);
            float val;
            if (G < 64) val = Wpost2[(t*832 + G)*32 + col];
            else {
                int g2 = G - 64;
                val = Wpost2[(t*832 +  64 + g2)*32 + col]
                    + AMP*Wpost2[(t*832 + 320 + g2)*32 + col]
                    + ATT*Wpost2[(t*832 + 576 + g2)*32 + col];
            }
            Wfp[jj] = f2h(val);
        } else {
            // Wfrag_lin: [kk<4][tile<8][lane<64][j<8], f16
            int jj = i - 73728;
            int kk = jj / 4096, r = jj % 4096;
            int tile = r >> 9, lane = (r >> 3) & 63, jf = r & 7;
            int k   = kk*32 + ((lane >> 4) << 3) + jf;
            int col = tile*16 + (lane & 15);
            Wfl[jj] = f2h(Wlin2[k*128 + col]);
        }
    }
}

// ---------------------------------------------------------------- kNN part
__global__ __launch_bounds__(256) void knn_part_kernel(const float* __restrict__ pos, float2* __restrict__ part)
{
    __shared__ float4 cposS[128];
    const int b = blockIdx.x;
    const int g = b >> 3, h = (b >> 2) & 1, q = b & 3;
    const int gb = g * NPG;
    const int cbase = q * 128;
    if (threadIdx.x < 128) {
        int j = cbase + threadIdx.x;
        cposS[threadIdx.x] = make_float4(pos[(gb+j)*3+0], pos[(gb+j)*3+1], pos[(gb+j)*3+2], 0.f);
    }
    __syncthreads();
    const int i = h*256 + threadIdx.x;
    const float px = pos[(gb+i)*3+0], py = pos[(gb+i)*3+1], pz = pos[(gb+i)*3+2];
    float bd[KNB]; int bi[KNB];
#pragma unroll
    for (int e = 0; e < KNB; ++e) { bd[e] = 3.0e38f; bi[e] = -1; }
#pragma unroll 4
    for (int j = 0; j < 128; ++j) {
        float4 pj = cposS[j];
        float dx = px - pj.x, dy = py - pj.y, dz = pz - pj.z;
        float d2 = __fadd_rn(__fadd_rn(__fmul_rn(dx,dx), __fmul_rn(dy,dy)), __fmul_rn(dz,dz));
        if (cbase + j == i) d2 = __builtin_inff();
        bool cmp[KNB];
#pragma unroll
        for (int e = 0; e < KNB; ++e) cmp[e] = d2 < bd[e];
#pragma unroll
        for (int e = KNB-1; e >= 1; --e) {
            bd[e] = cmp[e-1] ? bd[e-1] : (cmp[e] ? d2 : bd[e]);
            bi[e] = cmp[e-1] ? bi[e-1] : (cmp[e] ? cbase + j : bi[e]);
        }
        bd[0] = cmp[0] ? d2 : bd[0];
        bi[0] = cmp[0] ? cbase + j : bi[0];
    }
    float2* dst = &part[((size_t)(g*NPG + i)*4 + q)*KNB];
#pragma unroll
    for (int e = 0; e < KNB; ++e) dst[e] = make_float2(bd[e], __int_as_float(bi[e]));
}

// ---------------------------------------------------------------- kNN merge
__global__ __launch_bounds__(256) void knn_merge_kernel(const float2* __restrict__ part, int* __restrict__ nbr)
{
    const int n = blockIdx.x*256 + threadIdx.x;
    const float4* p4 = (const float4*)&part[(size_t)n*28];
    float bd[KNB]; int bi[KNB];
#pragma unroll
    for (int e = 0; e < KNB; ++e) { bd[e] = 3.0e38f; bi[e] = -1; }
#pragma unroll
    for (int m4 = 0; m4 < 14; ++m4) {
        float4 pr = p4[m4];
#pragma unroll
        for (int half = 0; half < 2; ++half) {
            float d2  = half ? pr.z : pr.x;
            int   idx = __float_as_int(half ? pr.w : pr.y);
            bool cmp[KNB];
#pragma unroll
            for (int e = 0; e < KNB; ++e) cmp[e] = d2 < bd[e];
#pragma unroll
            for (int e = KNB-1; e >= 1; --e) {
                bd[e] = cmp[e-1] ? bd[e-1] : (cmp[e] ? d2 : bd[e]);
                bi[e] = cmp[e-1] ? bi[e-1] : (cmp[e] ? idx : bi[e]);
            }
            bd[0] = cmp[0] ? d2 : bd[0];
            bi[0] = cmp[0] ? idx : bi[0];
        }
    }
    const int gb = n & ~(NPG-1);
#pragma unroll
    for (int e = 0; e < KNB; ++e) nbr[n*KNB + e] = gb + bi[e];
}

// ---------------------------------------------------------------- layer1: u1,v1 [N,32]
__global__ __launch_bounds__(256) void a1_kernel(
    const float* __restrict__ x, const float* __restrict__ Wpre1, const float* __restrict__ bpre1,
    float* __restrict__ u1, float* __restrict__ v1)
{
    __shared__ float wS[512];
    __shared__ float bS[32];
    const int tid = threadIdx.x;
    wS[tid] = Wpre1[tid]; wS[tid+256] = Wpre1[tid+256];
    if (tid < 32) bS[tid] = bpre1[tid];
    __syncthreads();
    const int n  = blockIdx.x*8 + (tid>>5);
    const int tf = tid & 31;
    const int t = tf >> 3, f = tf & 7;
    float u = bS[tf], v = 0.f;
#pragma unroll
    for (int e = 0; e < 8; ++e) {
        float xv = x[n*8+e];
        u += xv * wS[(t*16 + e)*8 + f];
        v += xv * wS[(t*16 + 8 + e)*8 + f];
    }
    u1[n*32+tf] = u;
    v1[n*32+tf] = v;
}

// ---------------------------------------------------------------- layer1 fused (MFMA f16)
__global__ __launch_bounds__(256) void b1_kernel(
    const float* __restrict__ x, const int* __restrict__ nbr,
    const float* __restrict__ u1, const float* __restrict__ v1,
    const unsigned short* __restrict__ Wf1p, const unsigned short* __restrict__ Wf1l,
    float* __restrict__ y1)
{
    __shared__ int nbrsS[112];
    __shared__ __align__(16) unsigned short actS[64*72];
    __shared__ __align__(16) unsigned short postS[16*72];
    const int tid  = threadIdx.x;
    const int base = blockIdx.x * 16;
    if (tid < 112) nbrsS[tid] = nbr[base*7 + tid];
    for (int i = tid; i < 384; i += 256) {
        int r = i / 6, gq = i - 6*r;
        *(ushort4*)&actS[r*72 + 40 + gq*4] = make_ushort4(0,0,0,0);
    }
#pragma unroll
    for (int it = 0; it < 2; ++it) {
        int i = tid + it*256;
        int n = i >> 5, r2 = i & 31, t = r2 >> 3, f = r2 & 7;
        actS[(n*4 + t)*72 + f] = f2h(x[(base+n)*8 + f]);
    }
    __syncthreads();
    {
        const int n = tid >> 4, cp = tid & 15;
        const int tf0 = cp*2, t = tf0 >> 3, f0 = tf0 & 7;
        float2 uu = *(const float2*)&u1[(base+n)*32 + tf0];
        float s0=0.f,s1=0.f,q0=0.f,q1=0.f;
        float mn0=3e38f,mn1=3e38f,mx0=-3e38f,mx1=-3e38f;
#pragma unroll
        for (int e = 0; e < 7; ++e) {
            float2 vv = *(const float2*)&v1[nbrsS[n*7+e]*32 + tf0];
            s0 += vv.x; q0 += vv.x*vv.x; mn0 = fminf(mn0, vv.x); mx0 = fmaxf(mx0, vv.x);
            s1 += vv.y; q1 += vv.y*vv.y; mn1 = fminf(mn1, vv.y); mx1 = fmaxf(mx1, vv.y);
        }
        float me0 = s0*(1.f/7.f), me1 = s1*(1.f/7.f);
        float sd0 = sqrtf(fmaxf(q0*(1.f/7.f) - me0*me0, 0.f) + 1e-5f);
        float sd1 = sqrtf(fmaxf(q1*(1.f/7.f) - me1*me1, 0.f) + 1e-5f);
        const int row = (n*4 + t)*72;
        ushort2 w_;
        w_.x = f2h(uu.x + me0); w_.y = f2h(uu.y + me1); *(ushort2*)&actS[row +  8 + f0] = w_;
        w_.x = f2h(uu.x + mn0); w_.y = f2h(uu.y + mn1); *(ushort2*)&actS[row + 16 + f0] = w_;
        w_.x = f2h(uu.x + mx0); w_.y = f2h(uu.y + mx1); *(ushort2*)&actS[row + 24 + f0] = w_;
        w_.x = f2h(sd0);        w_.y = f2h(sd1);        *(ushort2*)&actS[row + 32 + f0] = w_;
    }
    __syncthreads();
    const int l = tid & 63, w = tid >> 6;
    const int lr = l & 15, lk = l >> 4;
    f32x4 acc = {0.f,0.f,0.f,0.f};
    {
        const f16x8* WB = (const f16x8*)Wf1p;
#pragma unroll
        for (int kk = 0; kk < 2; ++kk) {
            f16x8 a = *(const f16x8*)&actS[(lr*4 + w)*72 + kk*32 + lk*8];
            f16x8 b = WB[(w*2 + kk)*64 + l];
            acc = __builtin_amdgcn_mfma_f32_16x16x32_f16(a, b, acc, 0, 0, 0);
        }
    }
#pragma unroll
    for (int j = 0; j < 4; ++j)
        postS[(lk*4 + j)*72 + w*16 + lr] = f2h(acc[j]);
    __syncthreads();
    f32x4 d = {0.f,0.f,0.f,0.f};
    {
        const f16x8* WB = (const f16x8*)Wf1l;
#pragma unroll
        for (int kk = 0; kk < 2; ++kk) {
            f16x8 a = *(const f16x8*)&postS[lr*72 + kk*32 + lk*8];
            f16x8 b = WB[(kk*4 + w)*64 + l];
            d = __builtin_amdgcn_mfma_f32_16x16x32_f16(a, b, d, 0, 0, 0);
        }
    }
#pragma unroll
    for (int j = 0; j < 4; ++j)
        y1[(base + lk*4 + j)*64 + w*16 + lr] = d[j];
}

// ---------------------------------------------------------------- BN stats fp32 input (y1)
template<int C>
__global__ __launch_bounds__(256) void bn_stats_kernel(
    const float* __restrict__ y, float* __restrict__ Ps, float* __restrict__ Pq)
{
    constexpr int IT     = (NN/1024)*(C/4)/256;
    constexpr int GROUPS = C/4;
    constexpr int REPS   = 256/GROUPS;
    const int tid = threadIdx.x;
    const float4* y4 = (const float4*)y + (size_t)blockIdx.x*256*IT;
    float4 s = make_float4(0.f,0.f,0.f,0.f), q = make_float4(0.f,0.f,0.f,0.f);
#pragma unroll
    for (int it = 0; it < IT; ++it) {
        float4 v = y4[it*256 + tid];
        s.x += v.x; s.y += v.y; s.z += v.z; s.w += v.w;
        q.x += v.x*v.x; q.y += v.y*v.y; q.z += v.z*v.z; q.w += v.w*v.w;
    }
    __shared__ float4 sS[256], qS[256];
    sS[tid] = s; qS[tid] = q;
    __syncthreads();
#pragma unroll
    for (int step = REPS/2; step >= 1; step >>= 1) {
        if (tid < step*GROUPS) {
            float4 s2 = sS[tid + step*GROUPS], q2 = qS[tid + step*GROUPS];
            float4 ss = sS[tid], qq = qS[tid];
            ss.x += s2.x; ss.y += s2.y; ss.z += s2.z; ss.w += s2.w;
            qq.x += q2.x; qq.y += q2.y; qq.z += q2.z; qq.w += q2.w;
            sS[tid] = ss; qS[tid] = qq;
        }
        __syncthreads();
    }
    if (tid < GROUPS) {
        ((float4*)&Ps[(size_t)blockIdx.x*C])[tid] = sS[tid];
        ((float4*)&Pq[(size_t)blockIdx.x*C])[tid] = qS[tid];
    }
}

// ---------------------------------------------------------------- BN stats f16 input (y2h), C=128
__global__ __launch_bounds__(256) void bn_stats_h_kernel(
    const unsigned short* __restrict__ yh, float* __restrict__ Ps, float* __restrict__ Pq)
{
    const int tid = threadIdx.x;
    const int rg = tid >> 4, cgg = tid & 15;
    float s[8], q[8];
#pragma unroll
    for (int j = 0; j < 8; ++j) { s[j] = 0.f; q[j] = 0.f; }
    const size_t rowBase = (size_t)blockIdx.x * 64;
#pragma unroll
    for (int it = 0; it < 4; ++it) {
        const int r = it*16 + rg;
        uint4 vv = *(const uint4*)&yh[(rowBase + r)*128 + cgg*8];
        unsigned wds[4] = {vv.x, vv.y, vv.z, vv.w};
#pragma unroll
        for (int p = 0; p < 4; ++p) {
            h2 v = __builtin_bit_cast(h2, wds[p]);
            float f0 = (float)v[0], f1 = (float)v[1];
            s[p*2]   += f0; q[p*2]   += f0*f0;
            s[p*2+1] += f1; q[p*2+1] += f1*f1;
        }
    }
    __shared__ float sS[256*8], qS[256*8];
#pragma unroll
    for (int j = 0; j < 8; ++j) { sS[tid*8+j] = s[j]; qS[tid*8+j] = q[j]; }
    __syncthreads();
#pragma unroll
    for (int step = 8; step >= 1; step >>= 1) {
        if (rg < step) {
            const int o = (tid + step*16)*8;
#pragma unroll
            for (int j = 0; j < 8; ++j) { sS[tid*8+j] += sS[o+j]; qS[tid*8+j] += qS[o+j]; }
        }
        __syncthreads();
    }
    if (rg == 0) {
#pragma unroll
        for (int j = 0; j < 8; ++j) {
            Ps[(size_t)blockIdx.x*128 + cgg*8 + j] = sS[tid*8+j];
            Pq[(size_t)blockIdx.x*128 + cgg*8 + j] = qS[tid*8+j];
        }
    }
}

// ---------------------------------------------------------------- finA: 64 blocks, sum 16 partial-rows
template<int C>
__global__ __launch_bounds__(C) void finA_kernel(
    const float* __restrict__ Ps, const float* __restrict__ Pq,
    float* __restrict__ As, float* __restrict__ Aq)
{
    const int c = threadIdx.x, b = blockIdx.x;
    float s = 0.f, q = 0.f;
#pragma unroll
    for (int i = 0; i < 16; ++i) {
        s += Ps[(b*16 + i)*C + c];
        q += Pq[(b*16 + i)*C + c];
    }
    As[b*C + c] = s;
    Aq[b*C + c] = q;
}

// ---------------------------------------------------------------- finalize BN -> scale/shift
template<int C>
__global__ __launch_bounds__(C) void fin_kernel(
    const float* __restrict__ As, const float* __restrict__ Aq,
    const float* __restrict__ g, const float* __restrict__ b,
    float* __restrict__ scO, float* __restrict__ shO)
{
    const int c = threadIdx.x;
    float s = 0.f, q = 0.f;
#pragma unroll 8
    for (int i = 0; i < 64; ++i) { s += As[i*C + c]; q += Aq[i*C + c]; }
    const float inv = 1.f/(float)NN;
    float mu  = s*inv;
    float var = q*inv - mu*mu;
    float sc  = g[c]*rsqrtf(var + 1e-5f);
    scO[c] = sc;
    shO[c] = b[c] - mu*sc;
}

// ---------------------------------------------------------------- layer2 pre (MFMA f16): v2 [N][256] f16
__global__ __launch_bounds__(256) void a2_kernel(
    const float* __restrict__ y1raw, const float* __restrict__ sc1, const float* __restrict__ sh1,
    const unsigned short* __restrict__ Wfv,
    unsigned short* __restrict__ v2)
{
    __shared__ __align__(16) unsigned short a1S[64*72];
    const int tid  = threadIdx.x;
    const int base = blockIdx.x * 64;
#pragma unroll
    for (int it = 0; it < 4; ++it) {
        int i = tid + it*256;
        float4 vv = ((const float4*)y1raw)[blockIdx.x*1024 + i];
        int n = i >> 4, c0 = (i & 15)*4;
        float c_[4] = {vv.x, vv.y, vv.z, vv.w};
#pragma unroll
        for (int j = 0; j < 4; ++j) {
            int c = c0 + j;
            a1S[n*72 + c] = f2h(fmaxf(c_[j]*sc1[c] + sh1[c], 0.f));
        }
    }
    __syncthreads();
    const int l = tid & 63, w = tid >> 6;
    const int lr = l & 15, lk = l >> 4;
    const f16x8 a0  = *(const f16x8*)&a1S[(w*16 + lr)*72 +      lk*8];
    const f16x8 a1f = *(const f16x8*)&a1S[(w*16 + lr)*72 + 32 + lk*8];
    const f16x8* WB = (const f16x8*)Wfv;
#pragma unroll 4
    for (int ct = 0; ct < 16; ++ct) {
        f32x4 acc = {0.f,0.f,0.f,0.f};
        f16x8 b0 = WB[ct*64 + l];
        f16x8 b1 = WB[(16 + ct)*64 + l];
        acc = __builtin_amdgcn_mfma_f32_16x16x32_f16(a0,  b0, acc, 0, 0, 0);
        acc = __builtin_amdgcn_mfma_f32_16x16x32_f16(a1f, b1, acc, 0, 0, 0);
        const int col = ct*16 + lr;
#pragma unroll
        for (int j = 0; j < 4; ++j)
            v2[(size_t)(base + w*16 + lk*4 + j)*256 + col] = f2h(acc[j]);
    }
}

// ---------------------------------------------------------------- layer2 fused (MFMA f16): agg + post(+ufold) + lin -> y2h
__global__ __launch_bounds__(256) void b2_kernel(
    const int* __restrict__ nbr, const float* __restrict__ y1raw,
    const float* __restrict__ sc1, const float* __restrict__ sh1,
    const unsigned short* __restrict__ v2,
    const unsigned short* __restrict__ Wfu,
    const unsigned short* __restrict__ Wfp, const unsigned short* __restrict__ Wfl,
    unsigned short* __restrict__ y2h)
{
    __shared__ int nbrsS[112];
    __shared__ __align__(16) unsigned short a1S[16*72];
    __shared__ __align__(16) unsigned short aggS[64*264];   // postS aliased into aggS[0..2175]
    unsigned short* postS = aggS;                           // live only after extra barrier

    const int tid = threadIdx.x;
    const int ob   = blockIdx.x;
    const int xcd  = ob & 7, slot = ob >> 3;
    const int gph  = ((slot >> 5) << 3) + xcd;
    const int sub  = slot & 31;
    const int base = gph*NPG + sub*16;

    if (tid < 112) nbrsS[tid] = nbr[base*7 + tid];
    for (int i = tid; i < 1024; i += 256) {
        int c = i & 63, n = i >> 6;
        float a = fmaxf(y1raw[base*64 + i]*sc1[c] + sh1[c], 0.f);
        a1S[n*72 + c] = f2h(a);
    }
    __syncthreads();
    // ---- aggregation: 16B (ushort8) gathers, 8 cols/thread, 8 node-slots x 2 iters
    {
        const int ns = tid >> 5, cg = tid & 31;
        const int t = cg >> 3, f0 = (cg & 7) * 8;
        const h2 inv7 = { (_Float16)(1.f/7.f), (_Float16)(1.f/7.f) };
#pragma unroll
        for (int it = 0; it < 2; ++it) {
            const int ln = it*8 + ns;
            h2 z = { (_Float16)0.f, (_Float16)0.f };
            h2 s[4]  = {z,z,z,z};
            h2 q[4]  = {z,z,z,z};
            h2 mn[4], mx[4];
#pragma unroll
            for (int p = 0; p < 4; ++p) {
                mn[p] = h2{ (_Float16)65504.f, (_Float16)65504.f };
                mx[p] = h2{ (_Float16)-65504.f, (_Float16)-65504.f };
            }
#pragma unroll
            for (int e = 0; e < 7; ++e) {
                uint4 vv = *(const uint4*)&v2[(size_t)nbrsS[ln*7+e]*256 + cg*8];
                unsigned vw[4] = {vv.x, vv.y, vv.z, vv.w};
#pragma unroll
                for (int p = 0; p < 4; ++p) {
                    h2 v = __builtin_bit_cast(h2, vw[p]);
                    s[p] += v;
                    q[p] += v*v;
                    mn[p] = __builtin_elementwise_min(mn[p], v);
                    mx[p] = __builtin_elementwise_max(mx[p], v);
                }
            }
            unsigned meW[4], mnW[4], mxW[4], sdW[4];
#pragma unroll
            for (int p = 0; p < 4; ++p) {
                h2 me = s[p]*inv7;
                float m0 = (float)me[0], m1 = (float)me[1];
                float sd0 = sqrtf(fmaxf(fmaf((float)q[p][0], 1.f/7.f, -m0*m0), 0.f) + 1e-5f);
                float sd1 = sqrtf(fmaxf(fmaf((float)q[p][1], 1.f/7.f, -m1*m1), 0.f) + 1e-5f);
                h2 sd = { (_Float16)sd0, (_Float16)sd1 };
                meW[p] = __builtin_bit_cast(unsigned, me);
                mnW[p] = __builtin_bit_cast(unsigned, mn[p]);
                mxW[p] = __builtin_bit_cast(unsigned, mx[p]);
                sdW[p] = __builtin_bit_cast(unsigned, sd);
            }
            const int ro = (t*16 + ln)*264 + f0;
            *(uint4*)&aggS[ro      ] = make_uint4(meW[0], meW[1], meW[2], meW[3]);
            *(uint4*)&aggS[ro +  64] = make_uint4(mnW[0], mnW[1], mnW[2], mnW[3]);
            *(uint4*)&aggS[ro + 128] = make_uint4(mxW[0], mxW[1], mxW[2], mxW[3]);
            *(uint4*)&aggS[ro + 192] = make_uint4(sdW[0], sdW[1], sdW[2], sdW[3]);
        }
    }
    __syncthreads();
    const int l = tid & 63, w = tid >> 6;
    const int lr = l & 15, lk = l >> 4;
    // ---- post GEMM (tower w): 2 a1-direct + 2 a1-ufold + 8 agg chunks
    f32x4 acc0 = {0.f,0.f,0.f,0.f}, acc1 = {0.f,0.f,0.f,0.f};
    {
        const f16x8* WP = (const f16x8*)Wfp;
        const f16x8* WU = (const f16x8*)Wfu;
#pragma unroll
        for (int kk = 0; kk < 12; ++kk) {
            f16x8 a, b0, b1;
            if (kk < 2) {
                a  = *(const f16x8*)&a1S[lr*72 + kk*32 + lk*8];
                b0 = WP[((w*10 + kk)*2 + 0)*64 + l];
                b1 = WP[((w*10 + kk)*2 + 1)*64 + l];
            } else if (kk < 4) {
                a  = *(const f16x8*)&a1S[lr*72 + (kk-2)*32 + lk*8];
                b0 = WU[((w*2 + (kk-2))*2 + 0)*64 + l];
                b1 = WU[((w*2 + (kk-2))*2 + 1)*64 + l];
            } else {
                a  = *(const f16x8*)&aggS[(w*16 + lr)*264 + (kk-4)*32 + lk*8];
                b0 = WP[((w*10 + (kk-2))*2 + 0)*64 + l];
                b1 = WP[((w*10 + (kk-2))*2 + 1)*64 + l];
            }
            acc0 = __builtin_amdgcn_mfma_f32_16x16x32_f16(a, b0, acc0, 0, 0, 0);
            acc1 = __builtin_amdgcn_mfma_f32_16x16x32_f16(a, b1, acc1, 0, 0, 0);
        }
    }
    __syncthreads();    // all aggS reads complete before postS (aliased) writes
#pragma unroll
    for (int j = 0; j < 4; ++j) {
        const int row = lk*4 + j;
        postS[row*136 + w*32 +      lr] = f2h(acc0[j]);
        postS[row*136 + w*32 + 16 + lr] = f2h(acc1[j]);
    }
    __syncthreads();
    // ---- lin GEMM (cols 32w..32w+31): K=128; bias cancels in BN2
    f32x4 d0 = {0.f,0.f,0.f,0.f}, d1 = {0.f,0.f,0.f,0.f};
    {
        const f16x8* WB = (const f16x8*)Wfl;
#pragma unroll
        for (int kk = 0; kk < 4; ++kk) {
            f16x8 a = *(const f16x8*)&postS[lr*136 + kk*32 + lk*8];
            f16x8 b0 = WB[(kk*8 + 2*w + 0)*64 + l];
            f16x8 b1 = WB[(kk*8 + 2*w + 1)*64 + l];
            d0 = __builtin_amdgcn_mfma_f32_16x16x32_f16(a, b0, d0, 0, 0, 0);
            d1 = __builtin_amdgcn_mfma_f32_16x16x32_f16(a, b1, d1, 0, 0, 0);
        }
    }
#pragma unroll
    for (int j = 0; j < 4; ++j) {
        const int row = lk*4 + j;
        y2h[(size_t)(base + row)*128 + w*32 +      lr] = f2h(d0[j]);
        y2h[(size_t)(base + row)*128 + w*32 + 16 + lr] = f2h(d1[j]);
    }
}

// ---------------------------------------------------------------- pool part (f16 y2)
__global__ __launch_bounds__(128) void pool_part_h_kernel(
    const unsigned short* __restrict__ y2h, const float* __restrict__ sc2, const float* __restrict__ sh2,
    float* __restrict__ Pp)
{
    const int c = threadIdx.x;
    const int b = blockIdx.x;
    const float sc = sc2[c];
    const float sh = sh2[c];
    float acc = 0.f;
    const size_t base = (size_t)b*64*128 + c;
#pragma unroll 4
    for (int i = 0; i < 64; ++i)
        acc += fmaxf(h2f(y2h[base + (size_t)i*128])*sc + sh, 0.f);
    Pp[b*128 + c] = acc;
}

// ---------------------------------------------------------------- pool finalize
__global__ __launch_bounds__(128) void pool_fin_kernel(
    const float* __restrict__ Pp, float* __restrict__ out)
{
    const int c = threadIdx.x, g = blockIdx.x;
    float acc = 0.f;
#pragma unroll
    for (int i = 0; i < 8; ++i) acc += Pp[(g*8 + i)*128 + c];
    out[g*128 + c] = acc * (1.f/(float)NPG);
}

// ---------------------------------------------------------------- launcher
extern "C" void kernel_launch(void* const* d_in, const int* in_sizes, int n_in,
                              void* d_out, int out_size, void* d_ws, size_t ws_size,
                              hipStream_t stream)
{
    const float* x      = (const float*)d_in[0];
    const float* pos    = (const float*)d_in[1];
    const float* Wpre1  = (const float*)d_in[2];
    const float* bpre1  = (const float*)d_in[3];
    const float* Wpost1 = (const float*)d_in[4];
    const float* bpost1 = (const float*)d_in[5];
    const float* Wlin1  = (const float*)d_in[6];
    const float* blin1  = (const float*)d_in[7];
    const float* bn1g   = (const float*)d_in[8];
    const float* bn1b   = (const float*)d_in[9];
    const float* Wpre2  = (const float*)d_in[10];
    const float* bpre2  = (const float*)d_in[11];
    const float* Wpost2 = (const float*)d_in[12];
    const float* bpost2 = (const float*)d_in[13];
    const float* Wlin2  = (const float*)d_in[14];
    const float* blin2  = (const float*)d_in[15];
    const float* bn2g   = (const float*)d_in[16];
    const float* bn2b   = (const float*)d_in[17];
    float* out = (float*)d_out;
    (void)bpost1; (void)blin1; (void)bpre2; (void)bpost2; (void)blin2;  // cancel in BN

    char* ws = (char*)d_ws;
    size_t off = 0;
    auto alloc = [&](size_t bytes) { void* p = ws + off; off += (bytes + 255) & ~(size_t)255; return p; };
    int*    nbr  = (int*)   alloc((size_t)NN*7*4);
    float2* part = (float2*)alloc((size_t)NN*28*8);
    float* u1    = (float*)alloc((size_t)NN*32*4);
    float* v1    = (float*)alloc((size_t)NN*32*4);
    float* y1    = (float*)alloc((size_t)NN*64*4);
    unsigned short* v2  = (unsigned short*)alloc((size_t)NN*256*2);
    unsigned short* y2h = (unsigned short*)alloc((size_t)NN*128*2);
    unsigned short* Wf1p = (unsigned short*)alloc(4096*2);
    unsigned short* Wf1l = (unsigned short*)alloc(4096*2);
    unsigned short* Wfv = (unsigned short*)alloc(16384*2);
    unsigned short* Wfu = (unsigned short*)alloc(8192*2);
    unsigned short* Wfp = (unsigned short*)alloc(40960*2);
    unsigned short* Wfl = (unsigned short*)alloc(16384*2);
    float* Wusum = (float*)alloc(8192*4);
    float* P1s   = (float*)alloc(1024*64*4);
    float* P1q   = (float*)alloc(1024*64*4);
    float* A1s   = (float*)alloc(64*64*4);
    float* A1q   = (float*)alloc(64*64*4);
    float* sc1   = (float*)alloc(64*4);
    float* sh1   = (float*)alloc(64*4);
    float* P2s   = (float*)alloc(1024*128*4);
    float* P2q   = (float*)alloc(1024*128*4);
    float* A2s   = (float*)alloc(64*128*4);
    float* A2q   = (float*)alloc(64*128*4);
    float* sc2   = (float*)alloc(128*4);
    float* sh2   = (float*)alloc(128*4);
    float* Pp    = (float*)alloc(1024*128*4);

    prep0_kernel<<<32, 256, 0, stream>>>(Wpost2, Wusum);
    prep_kernel<<<128, 256, 0, stream>>>(Wpost1, Wpost2, Wpre2, Wlin2, Wlin1, Wusum,
                                         Wf1p, Wf1l, Wfv, Wfu, Wfp, Wfl);
    knn_part_kernel<<<NGRAPH*8, 256, 0, stream>>>(pos, part);
    knn_merge_kernel<<<NN/256, 256, 0, stream>>>(part, nbr);
    a1_kernel<<<NN/8, 256, 0, stream>>>(x, Wpre1, bpre1, u1, v1);
    b1_kernel<<<NN/16, 256, 0, stream>>>(x, nbr, u1, v1, Wf1p, Wf1l, y1);
    bn_stats_kernel<64><<<1024, 256, 0, stream>>>(y1, P1s, P1q);
    finA_kernel<64><<<64, 64, 0, stream>>>(P1s, P1q, A1s, A1q);
    fin_kernel<64><<<1, 64, 0, stream>>>(A1s, A1q, bn1g, bn1b, sc1, sh1);
    a2_kernel<<<NN/64, 256, 0, stream>>>(y1, sc1, sh1, Wfv, v2);
    b2_kernel<<<NN/16, 256, 0, stream>>>(nbr, y1, sc1, sh1, v2, Wfu, Wfp, Wfl, y2h);
    bn_stats_h_kernel<<<1024, 256, 0, stream>>>(y2h, P2s, P2q);
    finA_kernel<128><<<64, 128, 0, stream>>>(P2s, P2q, A2s, A2q);
    fin_kernel<128><<<1, 128, 0, stream>>>(A2s, A2q, bn2g, bn2b, sc2, sh2);
    pool_part_h_kernel<<<1024, 128, 0, stream>>>(y2h, sc2, sh2, Pp);
    pool_fin_kernel<<<NGRAPH, 128, 0, stream>>>(Pp, out);
}

// Round 20
// 162.615 us; speedup vs baseline: 1.1328x; 1.0054x over previous
//
#include <hip/hip_runtime.h>
#include <math.h>

// PNANet on MI355X, round 20: b2 agg deep-prefetch.
//  * Issue all 14 gathers (2 node-slots x 7 edges) into registers before any
//    stats math -> 2x memory-level parallelism per wave (VGPR 52 -> ~110,
//    still 4 waves/SIMD). Structure/layout identical to round 19 otherwise.

#define NGRAPH 128
#define NPG    512
#define NN     (NGRAPH*NPG)   // 65536
#define KNB    7

constexpr double AVG_DEG_LOG_D = 2.0239670479173344;  // (100*ln6+200*ln7+700*ln8)/1000
constexpr double LOG8_D        = 2.0794415416798357;

typedef _Float16 f16x8 __attribute__((ext_vector_type(8)));
typedef _Float16 h2    __attribute__((ext_vector_type(2)));
typedef float    f32x4 __attribute__((ext_vector_type(4)));

__device__ __forceinline__ unsigned short f2h(float x) {
    _Float16 h = (_Float16)x;
    return __builtin_bit_cast(unsigned short, h);
}
__device__ __forceinline__ float h2f(unsigned short u) {
    return (float)__builtin_bit_cast(_Float16, u);
}

// ---------------------------------------------------------------- prep0: Wusum[t][f][col]
__global__ __launch_bounds__(256) void prep0_kernel(
    const float* __restrict__ Wpost2, float* __restrict__ Wusum)
{
    const float AMP = (float)(LOG8_D / AVG_DEG_LOG_D);
    const float ATT = (float)(AVG_DEG_LOG_D / LOG8_D);
    const int i = blockIdx.x*256 + threadIdx.x;       // 8192 = 4*64*32
    const int t = i >> 11, f = (i >> 5) & 63, col = i & 31;
    float wu = 0.f;
#pragma unroll
    for (int s = 0; s < 3; ++s) {
        int g2 = s*64 + f;
        wu += Wpost2[(t*832 +  64 + g2)*32 + col]
            + AMP*Wpost2[(t*832 + 320 + g2)*32 + col]
            + ATT*Wpost2[(t*832 + 576 + g2)*32 + col];
    }
    Wusum[i] = wu;
}

// ---------------------------------------------------------------- weight prep
__global__ __launch_bounds__(256) void prep_kernel(
    const float* __restrict__ Wpost1, const float* __restrict__ Wpost2,
    const float* __restrict__ Wpre2,  const float* __restrict__ Wlin2,
    const float* __restrict__ Wlin1,  const float* __restrict__ Wusum,
    unsigned short* __restrict__ Wf1p, unsigned short* __restrict__ Wf1l,
    unsigned short* __restrict__ Wfv, unsigned short* __restrict__ Wfu,
    unsigned short* __restrict__ Wfp, unsigned short* __restrict__ Wfl)
{
    const float AMP = (float)(LOG8_D / AVG_DEG_LOG_D);
    const float ATT = (float)(AVG_DEG_LOG_D / LOG8_D);
    for (int i = blockIdx.x*256 + threadIdx.x; i < 90112; i += gridDim.x*256) {
        if (i < 4096) {
            int t = i >> 10, kk = (i >> 9) & 1, lane = (i >> 3) & 63, j = i & 7;
            int k = kk*32 + ((lane >> 4) << 3) + j;
            int col = lane & 15;
            float val;
            if (k < 8)       val = Wpost1[(t*104 + k)*16 + col];
            else if (k < 40) {
                int g2 = k - 8;
                val = Wpost1[(t*104 +  8 + g2)*16 + col]
                    + AMP*Wpost1[(t*104 + 40 + g2)*16 + col]
                    + ATT*Wpost1[(t*104 + 72 + g2)*16 + col];
            } else val = 0.f;
            Wf1p[i] = f2h(val);
        } else if (i < 8192) {
            int jj = i - 4096;
            int kk = jj >> 11, tile = (jj >> 9) & 3, lane = (jj >> 3) & 63, j = jj & 7;
            int k = kk*32 + ((lane >> 4) << 3) + j;
            int col = tile*16 + (lane & 15);
            Wf1l[jj] = f2h(Wlin1[k*64 + col]);
        } else if (i < 24576) {
            int jj = i - 8192;
            int kk = jj >> 13, ct = (jj >> 9) & 15, lane = (jj >> 3) & 63, jf = jj & 7;
            int k   = kk*32 + ((lane >> 4) << 3) + jf;
            int col = ct*16 + (lane & 15);
            int t = col >> 6, f = col & 63;
            Wfv[jj] = f2h(Wpre2[(t*128 + 64 + k)*64 + f]);
        } else if (i < 32768) {
            int jj = i - 24576;
            int t = jj >> 11, kk = (jj >> 10) & 1, c = (jj >> 9) & 1, lane = (jj >> 3) & 63, jf = jj & 7;
            int k   = kk*32 + ((lane >> 4) << 3) + jf;
            int col = c*16 + (lane & 15);
            float acc = 0.f;
            for (int f = 0; f < 64; ++f)
                acc += Wpre2[(t*128 + k)*64 + f] * Wusum[(t*64 + f)*32 + col];
            Wfu[jj] = f2h(acc);
        } else if (i < 73728) {
            int jj = i - 32768;
            int t = jj / 10240, r = jj % 10240;
            int kk = r / 1024, r2 = r % 1024;
            int c = r2 >> 9, lane = (r2 >> 3) & 63, jf = r2 & 7;
            int G   = kk*32 + ((lane >> 4) << 3) + jf;
            int col = c*16 + (lane & 15);
            float val;
            if (G < 64) val = Wpost2[(t*832 + G)*32 + col];
            else {
                int g2 = G - 64;
                val = Wpost2[(t*832 +  64 + g2)*32 + col]
                    + AMP*Wpost2[(t*832 + 320 + g2)*32 + col]
                    + ATT*Wpost2[(t*832 + 576 + g2)*32 + col];
            }
            Wfp[jj] = f2h(val);
        } else {
            int jj = i - 73728;
            int kk = jj / 4096, r = jj % 4096;
            int tile = r >> 9, lane = (r >> 3) & 63, jf = r & 7;
            int k   = kk*32 + ((lane >> 4) << 3) + jf;
            int col = tile*16 + (lane & 15);
            Wfl[jj] = f2h(Wlin2[k*128 + col]);
        }
    }
}

// ---------------------------------------------------------------- kNN part
__global__ __launch_bounds__(256) void knn_part_kernel(const float* __restrict__ pos, float2* __restrict__ part)
{
    __shared__ float4 cposS[128];
    const int b = blockIdx.x;
    const int g = b >> 3, h = (b >> 2) & 1, q = b & 3;
    const int gb = g * NPG;
    const int cbase = q * 128;
    if (threadIdx.x < 128) {
        int j = cbase + threadIdx.x;
        cposS[threadIdx.x] = make_float4(pos[(gb+j)*3+0], pos[(gb+j)*3+1], pos[(gb+j)*3+2], 0.f);
    }
    __syncthreads();
    const int i = h*256 + threadIdx.x;
    const float px = pos[(gb+i)*3+0], py = pos[(gb+i)*3+1], pz = pos[(gb+i)*3+2];
    float bd[KNB]; int bi[KNB];
#pragma unroll
    for (int e = 0; e < KNB; ++e) { bd[e] = 3.0e38f; bi[e] = -1; }
#pragma unroll 4
    for (int j = 0; j < 128; ++j) {
        float4 pj = cposS[j];
        float dx = px - pj.x, dy = py - pj.y, dz = pz - pj.z;
        float d2 = __fadd_rn(__fadd_rn(__fmul_rn(dx,dx), __fmul_rn(dy,dy)), __fmul_rn(dz,dz));
        if (cbase + j == i) d2 = __builtin_inff();
        bool cmp[KNB];
#pragma unroll
        for (int e = 0; e < KNB; ++e) cmp[e] = d2 < bd[e];
#pragma unroll
        for (int e = KNB-1; e >= 1; --e) {
            bd[e] = cmp[e-1] ? bd[e-1] : (cmp[e] ? d2 : bd[e]);
            bi[e] = cmp[e-1] ? bi[e-1] : (cmp[e] ? cbase + j : bi[e]);
        }
        bd[0] = cmp[0] ? d2 : bd[0];
        bi[0] = cmp[0] ? cbase + j : bi[0];
    }
    float2* dst = &part[((size_t)(g*NPG + i)*4 + q)*KNB];
#pragma unroll
    for (int e = 0; e < KNB; ++e) dst[e] = make_float2(bd[e], __int_as_float(bi[e]));
}

// ---------------------------------------------------------------- kNN merge
__global__ __launch_bounds__(256) void knn_merge_kernel(const float2* __restrict__ part, int* __restrict__ nbr)
{
    const int n = blockIdx.x*256 + threadIdx.x;
    const float4* p4 = (const float4*)&part[(size_t)n*28];
    float bd[KNB]; int bi[KNB];
#pragma unroll
    for (int e = 0; e < KNB; ++e) { bd[e] = 3.0e38f; bi[e] = -1; }
#pragma unroll
    for (int m4 = 0; m4 < 14; ++m4) {
        float4 pr = p4[m4];
#pragma unroll
        for (int half = 0; half < 2; ++half) {
            float d2  = half ? pr.z : pr.x;
            int   idx = __float_as_int(half ? pr.w : pr.y);
            bool cmp[KNB];
#pragma unroll
            for (int e = 0; e < KNB; ++e) cmp[e] = d2 < bd[e];
#pragma unroll
            for (int e = KNB-1; e >= 1; --e) {
                bd[e] = cmp[e-1] ? bd[e-1] : (cmp[e] ? d2 : bd[e]);
                bi[e] = cmp[e-1] ? bi[e-1] : (cmp[e] ? idx : bi[e]);
            }
            bd[0] = cmp[0] ? d2 : bd[0];
            bi[0] = cmp[0] ? idx : bi[0];
        }
    }
    const int gb = n & ~(NPG-1);
#pragma unroll
    for (int e = 0; e < KNB; ++e) nbr[n*KNB + e] = gb + bi[e];
}

// ---------------------------------------------------------------- layer1: u1,v1 [N,32]
__global__ __launch_bounds__(256) void a1_kernel(
    const float* __restrict__ x, const float* __restrict__ Wpre1, const float* __restrict__ bpre1,
    float* __restrict__ u1, float* __restrict__ v1)
{
    __shared__ float wS[512];
    __shared__ float bS[32];
    const int tid = threadIdx.x;
    wS[tid] = Wpre1[tid]; wS[tid+256] = Wpre1[tid+256];
    if (tid < 32) bS[tid] = bpre1[tid];
    __syncthreads();
    const int n  = blockIdx.x*8 + (tid>>5);
    const int tf = tid & 31;
    const int t = tf >> 3, f = tf & 7;
    float u = bS[tf], v = 0.f;
#pragma unroll
    for (int e = 0; e < 8; ++e) {
        float xv = x[n*8+e];
        u += xv * wS[(t*16 + e)*8 + f];
        v += xv * wS[(t*16 + 8 + e)*8 + f];
    }
    u1[n*32+tf] = u;
    v1[n*32+tf] = v;
}

// ---------------------------------------------------------------- layer1 fused (MFMA f16)
__global__ __launch_bounds__(256) void b1_kernel(
    const float* __restrict__ x, const int* __restrict__ nbr,
    const float* __restrict__ u1, const float* __restrict__ v1,
    const unsigned short* __restrict__ Wf1p, const unsigned short* __restrict__ Wf1l,
    float* __restrict__ y1)
{
    __shared__ int nbrsS[112];
    __shared__ __align__(16) unsigned short actS[64*72];
    __shared__ __align__(16) unsigned short postS[16*72];
    const int tid  = threadIdx.x;
    const int base = blockIdx.x * 16;
    if (tid < 112) nbrsS[tid] = nbr[base*7 + tid];
    for (int i = tid; i < 384; i += 256) {
        int r = i / 6, gq = i - 6*r;
        *(ushort4*)&actS[r*72 + 40 + gq*4] = make_ushort4(0,0,0,0);
    }
#pragma unroll
    for (int it = 0; it < 2; ++it) {
        int i = tid + it*256;
        int n = i >> 5, r2 = i & 31, t = r2 >> 3, f = r2 & 7;
        actS[(n*4 + t)*72 + f] = f2h(x[(base+n)*8 + f]);
    }
    __syncthreads();
    {
        const int n = tid >> 4, cp = tid & 15;
        const int tf0 = cp*2, t = tf0 >> 3, f0 = tf0 & 7;
        float2 uu = *(const float2*)&u1[(base+n)*32 + tf0];
        float s0=0.f,s1=0.f,q0=0.f,q1=0.f;
        float mn0=3e38f,mn1=3e38f,mx0=-3e38f,mx1=-3e38f;
#pragma unroll
        for (int e = 0; e < 7; ++e) {
            float2 vv = *(const float2*)&v1[nbrsS[n*7+e]*32 + tf0];
            s0 += vv.x; q0 += vv.x*vv.x; mn0 = fminf(mn0, vv.x); mx0 = fmaxf(mx0, vv.x);
            s1 += vv.y; q1 += vv.y*vv.y; mn1 = fminf(mn1, vv.y); mx1 = fmaxf(mx1, vv.y);
        }
        float me0 = s0*(1.f/7.f), me1 = s1*(1.f/7.f);
        float sd0 = sqrtf(fmaxf(q0*(1.f/7.f) - me0*me0, 0.f) + 1e-5f);
        float sd1 = sqrtf(fmaxf(q1*(1.f/7.f) - me1*me1, 0.f) + 1e-5f);
        const int row = (n*4 + t)*72;
        ushort2 w_;
        w_.x = f2h(uu.x + me0); w_.y = f2h(uu.y + me1); *(ushort2*)&actS[row +  8 + f0] = w_;
        w_.x = f2h(uu.x + mn0); w_.y = f2h(uu.y + mn1); *(ushort2*)&actS[row + 16 + f0] = w_;
        w_.x = f2h(uu.x + mx0); w_.y = f2h(uu.y + mx1); *(ushort2*)&actS[row + 24 + f0] = w_;
        w_.x = f2h(sd0);        w_.y = f2h(sd1);        *(ushort2*)&actS[row + 32 + f0] = w_;
    }
    __syncthreads();
    const int l = tid & 63, w = tid >> 6;
    const int lr = l & 15, lk = l >> 4;
    f32x4 acc = {0.f,0.f,0.f,0.f};
    {
        const f16x8* WB = (const f16x8*)Wf1p;
#pragma unroll
        for (int kk = 0; kk < 2; ++kk) {
            f16x8 a = *(const f16x8*)&actS[(lr*4 + w)*72 + kk*32 + lk*8];
            f16x8 b = WB[(w*2 + kk)*64 + l];
            acc = __builtin_amdgcn_mfma_f32_16x16x32_f16(a, b, acc, 0, 0, 0);
        }
    }
#pragma unroll
    for (int j = 0; j < 4; ++j)
        postS[(lk*4 + j)*72 + w*16 + lr] = f2h(acc[j]);
    __syncthreads();
    f32x4 d = {0.f,0.f,0.f,0.f};
    {
        const f16x8* WB = (const f16x8*)Wf1l;
#pragma unroll
        for (int kk = 0; kk < 2; ++kk) {
            f16x8 a = *(const f16x8*)&postS[lr*72 + kk*32 + lk*8];
            f16x8 b = WB[(kk*4 + w)*64 + l];
            d = __builtin_amdgcn_mfma_f32_16x16x32_f16(a, b, d, 0, 0, 0);
        }
    }
#pragma unroll
    for (int j = 0; j < 4; ++j)
        y1[(base + lk*4 + j)*64 + w*16 + lr] = d[j];
}

// ---------------------------------------------------------------- BN stats fp32 input (y1)
template<int C>
__global__ __launch_bounds__(256) void bn_stats_kernel(
    const float* __restrict__ y, float* __restrict__ Ps, float* __restrict__ Pq)
{
    constexpr int IT     = (NN/1024)*(C/4)/256;
    constexpr int GROUPS = C/4;
    constexpr int REPS   = 256/GROUPS;
    const int tid = threadIdx.x;
    const float4* y4 = (const float4*)y + (size_t)blockIdx.x*256*IT;
    float4 s = make_float4(0.f,0.f,0.f,0.f), q = make_float4(0.f,0.f,0.f,0.f);
#pragma unroll
    for (int it = 0; it < IT; ++it) {
        float4 v = y4[it*256 + tid];
        s.x += v.x; s.y += v.y; s.z += v.z; s.w += v.w;
        q.x += v.x*v.x; q.y += v.y*v.y; q.z += v.z*v.z; q.w += v.w*v.w;
    }
    __shared__ float4 sS[256], qS[256];
    sS[tid] = s; qS[tid] = q;
    __syncthreads();
#pragma unroll
    for (int step = REPS/2; step >= 1; step >>= 1) {
        if (tid < step*GROUPS) {
            float4 s2 = sS[tid + step*GROUPS], q2 = qS[tid + step*GROUPS];
            float4 ss = sS[tid], qq = qS[tid];
            ss.x += s2.x; ss.y += s2.y; ss.z += s2.z; ss.w += s2.w;
            qq.x += q2.x; qq.y += q2.y; qq.z += q2.z; qq.w += q2.w;
            sS[tid] = ss; qS[tid] = qq;
        }
        __syncthreads();
    }
    if (tid < GROUPS) {
        ((float4*)&Ps[(size_t)blockIdx.x*C])[tid] = sS[tid];
        ((float4*)&Pq[(size_t)blockIdx.x*C])[tid] = qS[tid];
    }
}

// ---------------------------------------------------------------- BN stats f16 input (y2h), C=128
__global__ __launch_bounds__(256) void bn_stats_h_kernel(
    const unsigned short* __restrict__ yh, float* __restrict__ Ps, float* __restrict__ Pq)
{
    const int tid = threadIdx.x;
    const int rg = tid >> 4, cgg = tid & 15;
    float s[8], q[8];
#pragma unroll
    for (int j = 0; j < 8; ++j) { s[j] = 0.f; q[j] = 0.f; }
    const size_t rowBase = (size_t)blockIdx.x * 64;
#pragma unroll
    for (int it = 0; it < 4; ++it) {
        const int r = it*16 + rg;
        uint4 vv = *(const uint4*)&yh[(rowBase + r)*128 + cgg*8];
        unsigned wds[4] = {vv.x, vv.y, vv.z, vv.w};
#pragma unroll
        for (int p = 0; p < 4; ++p) {
            h2 v = __builtin_bit_cast(h2, wds[p]);
            float f0 = (float)v[0], f1 = (float)v[1];
            s[p*2]   += f0; q[p*2]   += f0*f0;
            s[p*2+1] += f1; q[p*2+1] += f1*f1;
        }
    }
    __shared__ float sS[256*8], qS[256*8];
#pragma unroll
    for (int j = 0; j < 8; ++j) { sS[tid*8+j] = s[j]; qS[tid*8+j] = q[j]; }
    __syncthreads();
#pragma unroll
    for (int step = 8; step >= 1; step >>= 1) {
        if (rg < step) {
            const int o = (tid + step*16)*8;
#pragma unroll
            for (int j = 0; j < 8; ++j) { sS[tid*8+j] += sS[o+j]; qS[tid*8+j] += qS[o+j]; }
        }
        __syncthreads();
    }
    if (rg == 0) {
#pragma unroll
        for (int j = 0; j < 8; ++j) {
            Ps[(size_t)blockIdx.x*128 + cgg*8 + j] = sS[tid*8+j];
            Pq[(size_t)blockIdx.x*128 + cgg*8 + j] = qS[tid*8+j];
        }
    }
}

// ---------------------------------------------------------------- finA
template<int C>
__global__ __launch_bounds__(C) void finA_kernel(
    const float* __restrict__ Ps, const float* __restrict__ Pq,
    float* __restrict__ As, float* __restrict__ Aq)
{
    const int c = threadIdx.x, b = blockIdx.x;
    float s = 0.f, q = 0.f;
#pragma unroll
    for (int i = 0; i < 16; ++i) {
        s += Ps[(b*16 + i)*C + c];
        q += Pq[(b*16 + i)*C + c];
    }
    As[b*C + c] = s;
    Aq[b*C + c] = q;
}

// ---------------------------------------------------------------- finalize BN -> scale/shift
template<int C>
__global__ __launch_bounds__(C) void fin_kernel(
    const float* __restrict__ As, const float* __restrict__ Aq,
    const float* __restrict__ g, const float* __restrict__ b,
    float* __restrict__ scO, float* __restrict__ shO)
{
    const int c = threadIdx.x;
    float s = 0.f, q = 0.f;
#pragma unroll 8
    for (int i = 0; i < 64; ++i) { s += As[i*C + c]; q += Aq[i*C + c]; }
    const float inv = 1.f/(float)NN;
    float mu  = s*inv;
    float var = q*inv - mu*mu;
    float sc  = g[c]*rsqrtf(var + 1e-5f);
    scO[c] = sc;
    shO[c] = b[c] - mu*sc;
}

// ---------------------------------------------------------------- layer2 pre (MFMA f16): v2 [N][256] f16
__global__ __launch_bounds__(256) void a2_kernel(
    const float* __restrict__ y1raw, const float* __restrict__ sc1, const float* __restrict__ sh1,
    const unsigned short* __restrict__ Wfv,
    unsigned short* __restrict__ v2)
{
    __shared__ __align__(16) unsigned short a1S[64*72];
    const int tid  = threadIdx.x;
    const int base = blockIdx.x * 64;
#pragma unroll
    for (int it = 0; it < 4; ++it) {
        int i = tid + it*256;
        float4 vv = ((const float4*)y1raw)[blockIdx.x*1024 + i];
        int n = i >> 4, c0 = (i & 15)*4;
        float c_[4] = {vv.x, vv.y, vv.z, vv.w};
#pragma unroll
        for (int j = 0; j < 4; ++j) {
            int c = c0 + j;
            a1S[n*72 + c] = f2h(fmaxf(c_[j]*sc1[c] + sh1[c], 0.f));
        }
    }
    __syncthreads();
    const int l = tid & 63, w = tid >> 6;
    const int lr = l & 15, lk = l >> 4;
    const f16x8 a0  = *(const f16x8*)&a1S[(w*16 + lr)*72 +      lk*8];
    const f16x8 a1f = *(const f16x8*)&a1S[(w*16 + lr)*72 + 32 + lk*8];
    const f16x8* WB = (const f16x8*)Wfv;
#pragma unroll 4
    for (int ct = 0; ct < 16; ++ct) {
        f32x4 acc = {0.f,0.f,0.f,0.f};
        f16x8 b0 = WB[ct*64 + l];
        f16x8 b1 = WB[(16 + ct)*64 + l];
        acc = __builtin_amdgcn_mfma_f32_16x16x32_f16(a0,  b0, acc, 0, 0, 0);
        acc = __builtin_amdgcn_mfma_f32_16x16x32_f16(a1f, b1, acc, 0, 0, 0);
        const int col = ct*16 + lr;
#pragma unroll
        for (int j = 0; j < 4; ++j)
            v2[(size_t)(base + w*16 + lk*4 + j)*256 + col] = f2h(acc[j]);
    }
}

// ---------------------------------------------------------------- layer2 fused (MFMA f16): agg + post(+ufold) + lin -> y2h
__global__ __launch_bounds__(256, 4) void b2_kernel(
    const int* __restrict__ nbr, const float* __restrict__ y1raw,
    const float* __restrict__ sc1, const float* __restrict__ sh1,
    const unsigned short* __restrict__ v2,
    const unsigned short* __restrict__ Wfu,
    const unsigned short* __restrict__ Wfp, const unsigned short* __restrict__ Wfl,
    unsigned short* __restrict__ y2h)
{
    __shared__ int nbrsS[112];
    __shared__ __align__(16) unsigned short a1S[16*72];
    __shared__ __align__(16) unsigned short aggS[64*264];   // postS aliased into aggS
    unsigned short* postS = aggS;

    const int tid = threadIdx.x;
    const int ob   = blockIdx.x;
    const int xcd  = ob & 7, slot = ob >> 3;
    const int gph  = ((slot >> 5) << 3) + xcd;
    const int sub  = slot & 31;
    const int base = gph*NPG + sub*16;

    if (tid < 112) nbrsS[tid] = nbr[base*7 + tid];
    for (int i = tid; i < 1024; i += 256) {
        int c = i & 63, n = i >> 6;
        float a = fmaxf(y1raw[base*64 + i]*sc1[c] + sh1[c], 0.f);
        a1S[n*72 + c] = f2h(a);
    }
    __syncthreads();
    // ---- aggregation: deep-prefetch all 14 gathers (2 slots x 7 edges) to regs
    {
        const int ns = tid >> 5, cg = tid & 31;
        const int t = cg >> 3, f0 = (cg & 7) * 8;
        const h2 inv7 = { (_Float16)(1.f/7.f), (_Float16)(1.f/7.f) };
        uint4 pre[2][7];
#pragma unroll
        for (int it = 0; it < 2; ++it) {
            const int ln = it*8 + ns;
#pragma unroll
            for (int e = 0; e < 7; ++e)
                pre[it][e] = *(const uint4*)&v2[(size_t)nbrsS[ln*7+e]*256 + cg*8];
        }
#pragma unroll
        for (int it = 0; it < 2; ++it) {
            const int ln = it*8 + ns;
            h2 z = { (_Float16)0.f, (_Float16)0.f };
            h2 s[4]  = {z,z,z,z};
            h2 q[4]  = {z,z,z,z};
            h2 mn[4], mx[4];
#pragma unroll
            for (int p = 0; p < 4; ++p) {
                mn[p] = h2{ (_Float16)65504.f, (_Float16)65504.f };
                mx[p] = h2{ (_Float16)-65504.f, (_Float16)-65504.f };
            }
#pragma unroll
            for (int e = 0; e < 7; ++e) {
                uint4 vv = pre[it][e];
                unsigned vw[4] = {vv.x, vv.y, vv.z, vv.w};
#pragma unroll
                for (int p = 0; p < 4; ++p) {
                    h2 v = __builtin_bit_cast(h2, vw[p]);
                    s[p] += v;
                    q[p] += v*v;
                    mn[p] = __builtin_elementwise_min(mn[p], v);
                    mx[p] = __builtin_elementwise_max(mx[p], v);
                }
            }
            unsigned meW[4], mnW[4], mxW[4], sdW[4];
#pragma unroll
            for (int p = 0; p < 4; ++p) {
                h2 me = s[p]*inv7;
                float m0 = (float)me[0], m1 = (float)me[1];
                float sd0 = sqrtf(fmaxf(fmaf((float)q[p][0], 1.f/7.f, -m0*m0), 0.f) + 1e-5f);
                float sd1 = sqrtf(fmaxf(fmaf((float)q[p][1], 1.f/7.f, -m1*m1), 0.f) + 1e-5f);
                h2 sd = { (_Float16)sd0, (_Float16)sd1 };
                meW[p] = __builtin_bit_cast(unsigned, me);
                mnW[p] = __builtin_bit_cast(unsigned, mn[p]);
                mxW[p] = __builtin_bit_cast(unsigned, mx[p]);
                sdW[p] = __builtin_bit_cast(unsigned, sd);
            }
            const int ro = (t*16 + ln)*264 + f0;
            *(uint4*)&aggS[ro      ] = make_uint4(meW[0], meW[1], meW[2], meW[3]);
            *(uint4*)&aggS[ro +  64] = make_uint4(mnW[0], mnW[1], mnW[2], mnW[3]);
            *(uint4*)&aggS[ro + 128] = make_uint4(mxW[0], mxW[1], mxW[2], mxW[3]);
            *(uint4*)&aggS[ro + 192] = make_uint4(sdW[0], sdW[1], sdW[2], sdW[3]);
        }
    }
    __syncthreads();
    const int l = tid & 63, w = tid >> 6;
    const int lr = l & 15, lk = l >> 4;
    // ---- post GEMM (tower w): 2 a1-direct + 2 a1-ufold + 8 agg chunks
    f32x4 acc0 = {0.f,0.f,0.f,0.f}, acc1 = {0.f,0.f,0.f,0.f};
    {
        const f16x8* WP = (const f16x8*)Wfp;
        const f16x8* WU = (const f16x8*)Wfu;
#pragma unroll
        for (int kk = 0; kk < 12; ++kk) {
            f16x8 a, b0, b1;
            if (kk < 2) {
                a  = *(const f16x8*)&a1S[lr*72 + kk*32 + lk*8];
                b0 = WP[((w*10 + kk)*2 + 0)*64 + l];
                b1 = WP[((w*10 + kk)*2 + 1)*64 + l];
            } else if (kk < 4) {
                a  = *(const f16x8*)&a1S[lr*72 + (kk-2)*32 + lk*8];
                b0 = WU[((w*2 + (kk-2))*2 + 0)*64 + l];
                b1 = WU[((w*2 + (kk-2))*2 + 1)*64 + l];
            } else {
                a  = *(const f16x8*)&aggS[(w*16 + lr)*264 + (kk-4)*32 + lk*8];
                b0 = WP[((w*10 + (kk-2))*2 + 0)*64 + l];
                b1 = WP[((w*10 + (kk-2))*2 + 1)*64 + l];
            }
            acc0 = __builtin_amdgcn_mfma_f32_16x16x32_f16(a, b0, acc0, 0, 0, 0);
            acc1 = __builtin_amdgcn_mfma_f32_16x16x32_f16(a, b1, acc1, 0, 0, 0);
        }
    }
    __syncthreads();    // all aggS reads complete before postS (aliased) writes
#pragma unroll
    for (int j = 0; j < 4; ++j) {
        const int row = lk*4 + j;
        postS[row*136 + w*32 +      lr] = f2h(acc0[j]);
        postS[row*136 + w*32 + 16 + lr] = f2h(acc1[j]);
    }
    __syncthreads();
    // ---- lin GEMM (cols 32w..32w+31): K=128; bias cancels in BN2
    f32x4 d0 = {0.f,0.f,0.f,0.f}, d1 = {0.f,0.f,0.f,0.f};
    {
        const f16x8* WB = (const f16x8*)Wfl;
#pragma unroll
        for (int kk = 0; kk < 4; ++kk) {
            f16x8 a = *(const f16x8*)&postS[lr*136 + kk*32 + lk*8];
            f16x8 b0 = WB[(kk*8 + 2*w + 0)*64 + l];
            f16x8 b1 = WB[(kk*8 + 2*w + 1)*64 + l];
            d0 = __builtin_amdgcn_mfma_f32_16x16x32_f16(a, b0, d0, 0, 0, 0);
            d1 = __builtin_amdgcn_mfma_f32_16x16x32_f16(a, b1, d1, 0, 0, 0);
        }
    }
#pragma unroll
    for (int j = 0; j < 4; ++j) {
        const int row = lk*4 + j;
        y2h[(size_t)(base + row)*128 + w*32 +      lr] = f2h(d0[j]);
        y2h[(size_t)(base + row)*128 + w*32 + 16 + lr] = f2h(d1[j]);
    }
}

// ---------------------------------------------------------------- pool part (f16 y2)
__global__ __launch_bounds__(128) void pool_part_h_kernel(
    const unsigned short* __restrict__ y2h, const float* __restrict__ sc2, const float* __restrict__ sh2,
    float* __restrict__ Pp)
{
    const int c = threadIdx.x;
    const int b = blockIdx.x;
    const float sc = sc2[c];
    const float sh = sh2[c];
    float acc = 0.f;
    const size_t base = (size_t)b*64*128 + c;
#pragma unroll 4
    for (int i = 0; i < 64; ++i)
        acc += fmaxf(h2f(y2h[base + (size_t)i*128])*sc + sh, 0.f);
    Pp[b*128 + c] = acc;
}

// ---------------------------------------------------------------- pool finalize
__global__ __launch_bounds__(128) void pool_fin_kernel(
    const float* __restrict__ Pp, float* __restrict__ out)
{
    const int c = threadIdx.x, g = blockIdx.x;
    float acc = 0.f;
#pragma unroll
    for (int i = 0; i < 8; ++i) acc += Pp[(g*8 + i)*128 + c];
    out[g*128 + c] = acc * (1.f/(float)NPG);
}

// ---------------------------------------------------------------- launcher
extern "C" void kernel_launch(void* const* d_in, const int* in_sizes, int n_in,
                              void* d_out, int out_size, void* d_ws, size_t ws_size,
                              hipStream_t stream)
{
    const float* x      = (const float*)d_in[0];
    const float* pos    = (const float*)d_in[1];
    const float* Wpre1  = (const float*)d_in[2];
    const float* bpre1  = (const float*)d_in[3];
    const float* Wpost1 = (const float*)d_in[4];
    const float* bpost1 = (const float*)d_in[5];
    const float* Wlin1  = (const float*)d_in[6];
    const float* blin1  = (const float*)d_in[7];
    const float* bn1g   = (const float*)d_in[8];
    const float* bn1b   = (const float*)d_in[9];
    const float* Wpre2  = (const float*)d_in[10];
    const float* bpre2  = (const float*)d_in[11];
    const float* Wpost2 = (const float*)d_in[12];
    const float* bpost2 = (const float*)d_in[13];
    const float* Wlin2  = (const float*)d_in[14];
    const float* blin2  = (const float*)d_in[15];
    const float* bn2g   = (const float*)d_in[16];
    const float* bn2b   = (const float*)d_in[17];
    float* out = (float*)d_out;
    (void)bpost1; (void)blin1; (void)bpre2; (void)bpost2; (void)blin2;  // cancel in BN

    char* ws = (char*)d_ws;
    size_t off = 0;
    auto alloc = [&](size_t bytes) { void* p = ws + off; off += (bytes + 255) & ~(size_t)255; return p; };
    int*    nbr  = (int*)   alloc((size_t)NN*7*4);
    float2* part = (float2*)alloc((size_t)NN*28*8);
    float* u1    = (float*)alloc((size_t)NN*32*4);
    float* v1    = (float*)alloc((size_t)NN*32*4);
    float* y1    = (float*)alloc((size_t)NN*64*4);
    unsigned short* v2  = (unsigned short*)alloc((size_t)NN*256*2);
    unsigned short* y2h = (unsigned short*)alloc((size_t)NN*128*2);
    unsigned short* Wf1p = (unsigned short*)alloc(4096*2);
    unsigned short* Wf1l = (unsigned short*)alloc(4096*2);
    unsigned short* Wfv = (unsigned short*)alloc(16384*2);
    unsigned short* Wfu = (unsigned short*)alloc(8192*2);
    unsigned short* Wfp = (unsigned short*)alloc(40960*2);
    unsigned short* Wfl = (unsigned short*)alloc(16384*2);
    float* Wusum = (float*)alloc(8192*4);
    float* P1s   = (float*)alloc(1024*64*4);
    float* P1q   = (float*)alloc(1024*64*4);
    float* A1s   = (float*)alloc(64*64*4);
    float* A1q   = (float*)alloc(64*64*4);
    float* sc1   = (float*)alloc(64*4);
    float* sh1   = (float*)alloc(64*4);
    float* P2s   = (float*)alloc(1024*128*4);
    float* P2q   = (float*)alloc(1024*128*4);
    float* A2s   = (float*)alloc(64*128*4);
    float* A2q   = (float*)alloc(64*128*4);
    float* sc2   = (float*)alloc(128*4);
    float* sh2   = (float*)alloc(128*4);
    float* Pp    = (float*)alloc(1024*128*4);

    prep0_kernel<<<32, 256, 0, stream>>>(Wpost2, Wusum);
    prep_kernel<<<128, 256, 0, stream>>>(Wpost1, Wpost2, Wpre2, Wlin2, Wlin1, Wusum,
                                         Wf1p, Wf1l, Wfv, Wfu, Wfp, Wfl);
    knn_part_kernel<<<NGRAPH*8, 256, 0, stream>>>(pos, part);
    knn_merge_kernel<<<NN/256, 256, 0, stream>>>(part, nbr);
    a1_kernel<<<NN/8, 256, 0, stream>>>(x, Wpre1, bpre1, u1, v1);
    b1_kernel<<<NN/16, 256, 0, stream>>>(x, nbr, u1, v1, Wf1p, Wf1l, y1);
    bn_stats_kernel<64><<<1024, 256, 0, stream>>>(y1, P1s, P1q);
    finA_kernel<64><<<64, 64, 0, stream>>>(P1s, P1q, A1s, A1q);
    fin_kernel<64><<<1, 64, 0, stream>>>(A1s, A1q, bn1g, bn1b, sc1, sh1);
    a2_kernel<<<NN/64, 256, 0, stream>>>(y1, sc1, sh1, Wfv, v2);
    b2_kernel<<<NN/16, 256, 0, stream>>>(nbr, y1, sc1, sh1, v2, Wfu, Wfp, Wfl, y2h);
    bn_stats_h_kernel<<<1024, 256, 0, stream>>>(y2h, P2s, P2q);
    finA_kernel<128><<<64, 128, 0, stream>>>(P2s, P2q, A2s, A2q);
    fin_kernel<128><<<1, 128, 0, stream>>>(A2s, A2q, bn2g, bn2b, sc2, sh2);
    pool_part_h_kernel<<<1024, 128, 0, stream>>>(y2h, sc2, sh2, Pp);
    pool_fin_kernel<<<NGRAPH, 128, 0, stream>>>(Pp, out);
}